// Round 1
// baseline (640.077 us; speedup 1.0000x reference)
//
#include <hip/hip_runtime.h>
#include <stdint.h>

#define DEV __device__ __forceinline__

typedef unsigned short u16;
typedef __bf16 bf16x8 __attribute__((ext_vector_type(8)));
typedef float  f32x4  __attribute__((ext_vector_type(4)));
typedef unsigned short u16x8 __attribute__((ext_vector_type(8)));
typedef unsigned short u16x4 __attribute__((ext_vector_type(4)));
typedef float  fvec4  __attribute__((ext_vector_type(4)));

constexpr int Sz   = 1024;  // sequence length
constexpr int Dm   = 1024;  // model dim
constexpr int NH   = 16;    // heads
constexpr int HDm  = 64;    // head dim
constexpr int NREL = 512;
constexpr int Mrows = 8192; // B*S

DEV u16 f2bf(float f) {
  uint32_t u = __builtin_bit_cast(uint32_t, f);
  uint32_t r = u + 0x7fffu + ((u >> 16) & 1u);
  return (u16)(r >> 16);
}
DEV float bf2f(u16 h) { return __builtin_bit_cast(float, (uint32_t)h << 16); }
DEV f32x4 mfma16(bf16x8 a, bf16x8 b, f32x4 c) {
  return __builtin_amdgcn_mfma_f32_16x16x32_bf16(a, b, c, 0, 0, 0);
}

// ---------------- fp32 -> bf16 conversion (weights) ----------------
__global__ __launch_bounds__(256) void cvt_kernel(const float* __restrict__ in,
                                                  u16* __restrict__ out) {
  size_t i = (size_t)blockIdx.x * 256 + threadIdx.x;
  fvec4 v = *(const fvec4*)(in + i * 4);
  u16x4 o;
  o[0] = f2bf(v[0]); o[1] = f2bf(v[1]); o[2] = f2bf(v[2]); o[3] = f2bf(v[3]);
  *(u16x4*)(out + i * 4) = o;
}

// ---------------- GEMM: C[m,n] = sum_k A[m,k]*Bw[n,k] + bias[n] ----------------
// A fp32 [8192,1024], Bw bf16 [1024,1024] (row-major = B^T form), out bf16 or fp32.
template<bool OUT_BF16>
__global__ __launch_bounds__(256) void gemm_bt(const float* __restrict__ A,
                                               const u16* __restrict__ Bw,
                                               const float* __restrict__ bias,
                                               void* __restrict__ Cout) {
  constexpr int BK = 64;
  __shared__ u16 As[128 * BK];
  __shared__ u16 Bs[128 * BK];
  const int tid = threadIdx.x;
  const int wave = tid >> 6, lane = tid & 63;
  const int lr = lane & 15, lg = lane >> 4;
  const int m0 = blockIdx.y * 128, n0 = blockIdx.x * 128;
  const int wr = (wave >> 1) * 64, wc = (wave & 1) * 64;
  f32x4 acc[4][4] = {};
  for (int k0 = 0; k0 < Dm; k0 += BK) {
    // B tile via async global->LDS (16B/lane), linear LDS layout [128][64]
    #pragma unroll
    for (int it = 0; it < 4; ++it) {
      int chunk = it * 256 + wave * 64 + lane;
      int row = chunk >> 3, c8 = (chunk & 7) * 8;
      const u16* src = Bw + (size_t)(n0 + row) * Dm + k0 + c8;
      __builtin_amdgcn_global_load_lds(
          (const __attribute__((address_space(1))) void*)src,
          (__attribute__((address_space(3))) void*)&Bs[(it * 256 + wave * 64) * 8],
          16, 0, 0);
    }
    // A tile reg-staged with fp32->bf16 convert
    #pragma unroll
    for (int it = 0; it < 4; ++it) {
      int chunk = it * 256 + tid;
      int row = chunk >> 3, c8 = (chunk & 7) * 8;
      const float* src = A + (size_t)(m0 + row) * Dm + k0 + c8;
      fvec4 lo = *(const fvec4*)src;
      fvec4 hi = *(const fvec4*)(src + 4);
      u16x8 v;
      v[0] = f2bf(lo[0]); v[1] = f2bf(lo[1]); v[2] = f2bf(lo[2]); v[3] = f2bf(lo[3]);
      v[4] = f2bf(hi[0]); v[5] = f2bf(hi[1]); v[6] = f2bf(hi[2]); v[7] = f2bf(hi[3]);
      *(u16x8*)&As[chunk * 8] = v;
    }
    __syncthreads();
    #pragma unroll
    for (int kk = 0; kk < BK; kk += 32) {
      bf16x8 af[4], bf_[4];
      #pragma unroll
      for (int m = 0; m < 4; ++m)
        af[m] = *(const bf16x8*)&As[(wr + m * 16 + lr) * BK + kk + lg * 8];
      #pragma unroll
      for (int n = 0; n < 4; ++n)
        bf_[n] = *(const bf16x8*)&Bs[(wc + n * 16 + lr) * BK + kk + lg * 8];
      #pragma unroll
      for (int m = 0; m < 4; ++m)
        #pragma unroll
        for (int n = 0; n < 4; ++n)
          acc[m][n] = mfma16(af[m], bf_[n], acc[m][n]);
    }
    __syncthreads();
  }
  float bv[4];
  #pragma unroll
  for (int n = 0; n < 4; ++n) bv[n] = bias[n0 + wc + n * 16 + lr];
  #pragma unroll
  for (int m = 0; m < 4; ++m) {
    #pragma unroll
    for (int n = 0; n < 4; ++n) {
      const int gcol = n0 + wc + n * 16 + lr;
      #pragma unroll
      for (int r = 0; r < 4; ++r) {
        const int grow = m0 + wr + m * 16 + lg * 4 + r;
        float v = acc[m][n][r] + bv[n];
        if (OUT_BF16)
          ((u16*)Cout)[(size_t)grow * Dm + gcol] = f2bf(v);
        else
          ((float*)Cout)[(size_t)grow * Dm + gcol] = v;
      }
    }
  }
}

// ---------------- fused causal attention with relative-position bias ----------------
// Block = 128 threads (2 waves). Each block: one (b,h), 32 query rows.
// Wave w owns q rows [qb + 16w, qb + 16w + 16). KV tiles of 64.
__global__ __launch_bounds__(128) void attn_kernel(const u16* __restrict__ Q,
                                                   const u16* __restrict__ Kb,
                                                   const u16* __restrict__ Vb,
                                                   const float* __restrict__ pos,
                                                   float* __restrict__ O) {
  __shared__ u16 REL[32][520];   // REL[q_local][r] = q . pos_table[r] (bf16)
  __shared__ u16 Ks[64 * 72];    // K tile row-major [j][d], stride 72
  __shared__ u16 Vt[64 * 72];    // V tile transposed [d][j], stride 72
  __shared__ u16 Pw[2][16 * 72]; // per-wave P tile [q][j], stride 72

  const int tid = threadIdx.x;
  const int wave = tid >> 6, lane = tid & 63;
  const int lr = lane & 15, lg = lane >> 4;
  const int bid = blockIdx.x;
  const int bh = bid >> 5;
  const int qi = 31 - (bid & 31);       // reversed: heavy blocks first
  const int b = bh >> 4, h = bh & 15;
  const int qb = qi * 32;
  const int wq = qb + wave * 16;

  // Q fragments for this wave's 16 rows (A operand, reused everywhere)
  const u16* qptr = Q + (size_t)(b * Sz + wq + lr) * Dm + h * HDm;
  bf16x8 qf[2];
  qf[0] = *(const bf16x8*)(qptr + lg * 8);
  qf[1] = *(const bf16x8*)(qptr + 32 + lg * 8);

  // --- REL rows via MFMA: REL[q, r] = sum_d Q[q,d] * pos[r,d] ---
  {
    int rmax = qb + 31; if (rmax > NREL - 1) rmax = NREL - 1;
    const int nrg = (rmax >> 4) + 1;
    for (int rg = 0; rg < nrg; ++rg) {
      f32x4 acc = {};
      #pragma unroll
      for (int kk = 0; kk < 2; ++kk) {
        const float* ps = pos + (size_t)(rg * 16 + lr) * HDm + kk * 32 + lg * 8;
        fvec4 p0 = *(const fvec4*)ps;
        fvec4 p1 = *(const fvec4*)(ps + 4);
        u16x8 pv;
        pv[0] = f2bf(p0[0]); pv[1] = f2bf(p0[1]); pv[2] = f2bf(p0[2]); pv[3] = f2bf(p0[3]);
        pv[4] = f2bf(p1[0]); pv[5] = f2bf(p1[1]); pv[6] = f2bf(p1[2]); pv[7] = f2bf(p1[3]);
        acc = mfma16(qf[kk], __builtin_bit_cast(bf16x8, pv), acc);
      }
      #pragma unroll
      for (int r = 0; r < 4; ++r)
        REL[wave * 16 + lg * 4 + r][rg * 16 + lr] = f2bf(acc[r]);
    }
  }

  f32x4 oacc[4] = {};
  float m_i[4], l_i[4];
  #pragma unroll
  for (int r = 0; r < 4; ++r) { m_i[r] = -1e30f; l_i[r] = 0.f; }

  const int ntiles = ((qb + 31) >> 6) + 1;
  for (int t = 0; t < ntiles; ++t) {
    const int j0 = t * 64;
    // stage K tile [64][72]
    #pragma unroll
    for (int it = 0; it < 4; ++it) {
      int chunk = it * 128 + tid;
      int row = chunk >> 3, c8 = (chunk & 7) * 8;
      u16x8 v = *(const u16x8*)(Kb + (size_t)(b * Sz + j0 + row) * Dm + h * HDm + c8);
      *(u16x8*)&Ks[row * 72 + c8] = v;
    }
    // stage V transposed [d][j]
    #pragma unroll
    for (int it = 0; it < 8; ++it) {
      int chunk = it * 128 + tid;
      int row = chunk >> 4, d0 = (chunk & 15) * 4;
      u16x4 v4 = *(const u16x4*)(Vb + (size_t)(b * Sz + j0 + row) * Dm + h * HDm + d0);
      Vt[(d0 + 0) * 72 + row] = v4[0];
      Vt[(d0 + 1) * 72 + row] = v4[1];
      Vt[(d0 + 2) * 72 + row] = v4[2];
      Vt[(d0 + 3) * 72 + row] = v4[3];
    }
    __syncthreads();

    // QK^T: S[16,64]
    f32x4 sacc[4];
    #pragma unroll
    for (int jg = 0; jg < 4; ++jg) {
      f32x4 a = {};
      #pragma unroll
      for (int kk = 0; kk < 2; ++kk) {
        bf16x8 kf = *(const bf16x8*)&Ks[(jg * 16 + lr) * 72 + kk * 32 + lg * 8];
        a = mfma16(qf[kk], kf, a);
      }
      sacc[jg] = a;
    }

    // bias gather + scale + mask, per-element
    float p[4][4], tmax[4];
    #pragma unroll
    for (int r = 0; r < 4; ++r) {
      tmax[r] = -3e38f;
      const int ig = wq + lg * 4 + r;
      #pragma unroll
      for (int jg = 0; jg < 4; ++jg) {
        const int jj = j0 + jg * 16 + lr;
        int rel = ig - jj;
        int rc = rel < 0 ? 0 : (rel > NREL - 1 ? NREL - 1 : rel);
        float bias = bf2f(REL[wave * 16 + lg * 4 + r][rc]);
        float s = (sacc[jg][r] + bias) * 0.125f;
        if (jj > ig) s = -1e9f;
        p[r][jg] = s;
        tmax[r] = fmaxf(tmax[r], s);
      }
    }
    #pragma unroll
    for (int msk = 1; msk < 16; msk <<= 1)
      #pragma unroll
      for (int r = 0; r < 4; ++r)
        tmax[r] = fmaxf(tmax[r], __shfl_xor(tmax[r], msk, 64));

    float scale[4];
    #pragma unroll
    for (int r = 0; r < 4; ++r) {
      float mn = fmaxf(m_i[r], tmax[r]);
      scale[r] = __expf(m_i[r] - mn);
      m_i[r] = mn;
    }
    float lsum[4];
    #pragma unroll
    for (int r = 0; r < 4; ++r) {
      float s0 = 0.f;
      #pragma unroll
      for (int jg = 0; jg < 4; ++jg) {
        p[r][jg] = __expf(p[r][jg] - m_i[r]);
        s0 += p[r][jg];
      }
      lsum[r] = s0;
    }
    #pragma unroll
    for (int msk = 1; msk < 16; msk <<= 1)
      #pragma unroll
      for (int r = 0; r < 4; ++r)
        lsum[r] += __shfl_xor(lsum[r], msk, 64);
    #pragma unroll
    for (int r = 0; r < 4; ++r) l_i[r] = l_i[r] * scale[r] + lsum[r];
    #pragma unroll
    for (int dg = 0; dg < 4; ++dg)
      #pragma unroll
      for (int r = 0; r < 4; ++r)
        oacc[dg][r] *= scale[r];

    // P -> LDS (bf16)
    #pragma unroll
    for (int r = 0; r < 4; ++r)
      #pragma unroll
      for (int jg = 0; jg < 4; ++jg)
        Pw[wave][(lg * 4 + r) * 72 + jg * 16 + lr] = f2bf(p[r][jg]);

    // PV: O[16,64] += P[16,64] @ V[64,64]
    #pragma unroll
    for (int kk = 0; kk < 2; ++kk) {
      bf16x8 pf = *(const bf16x8*)&Pw[wave][lr * 72 + kk * 32 + lg * 8];
      #pragma unroll
      for (int dg = 0; dg < 4; ++dg) {
        bf16x8 vf = *(const bf16x8*)&Vt[(dg * 16 + lr) * 72 + kk * 32 + lg * 8];
        oacc[dg] = mfma16(pf, vf, oacc[dg]);
      }
    }
    __syncthreads();
  }

  // epilogue: normalize and store fp32
  #pragma unroll
  for (int r = 0; r < 4; ++r) {
    float inv = 1.0f / l_i[r];
    size_t orow = (size_t)(b * Sz + wq + lg * 4 + r) * Dm + h * HDm;
    #pragma unroll
    for (int dg = 0; dg < 4; ++dg)
      O[orow + dg * 16 + lr] = oacc[dg][r] * inv;
  }
}

// ---------------- launcher ----------------
extern "C" void kernel_launch(void* const* d_in, const int* in_sizes, int n_in,
                              void* d_out, int out_size, void* d_ws, size_t ws_size,
                              hipStream_t stream) {
  const float* query = (const float*)d_in[0];
  const float* key   = (const float*)d_in[1];
  const float* value = (const float*)d_in[2];
  const float* Wq    = (const float*)d_in[3];
  const float* bq    = (const float*)d_in[4];
  const float* Wk    = (const float*)d_in[5];
  const float* bk    = (const float*)d_in[6];
  const float* Wv    = (const float*)d_in[7];
  const float* bv    = (const float*)d_in[8];
  const float* Wo    = (const float*)d_in[9];
  const float* bo    = (const float*)d_in[10];
  const float* pos   = (const float*)d_in[11];

  char* ws = (char*)d_ws;
  u16*   WqB = (u16*)(ws);
  u16*   WkB = (u16*)(ws + (2ull << 20));
  u16*   WvB = (u16*)(ws + (4ull << 20));
  u16*   WoB = (u16*)(ws + (6ull << 20));
  u16*   Qb  = (u16*)(ws + (8ull << 20));
  u16*   Kb  = (u16*)(ws + (24ull << 20));
  u16*   Vb  = (u16*)(ws + (40ull << 20));
  float* Ob  = (float*)(ws + (56ull << 20));

  // weights fp32 -> bf16
  cvt_kernel<<<1024, 256, 0, stream>>>(Wq, WqB);
  cvt_kernel<<<1024, 256, 0, stream>>>(Wk, WkB);
  cvt_kernel<<<1024, 256, 0, stream>>>(Wv, WvB);
  cvt_kernel<<<1024, 256, 0, stream>>>(Wo, WoB);

  // projections
  dim3 ggrid(Dm / 128, Mrows / 128);
  gemm_bt<true><<<ggrid, 256, 0, stream>>>(query, WqB, bq, Qb);
  gemm_bt<true><<<ggrid, 256, 0, stream>>>(key,   WkB, bk, Kb);
  gemm_bt<true><<<ggrid, 256, 0, stream>>>(value, WvB, bv, Vb);

  // fused attention (B*H*32 q-blocks)
  attn_kernel<<<4096, 128, 0, stream>>>(Qb, Kb, Vb, pos, Ob);

  // output projection -> fp32 d_out
  gemm_bt<false><<<ggrid, 256, 0, stream>>>(Ob, WoB, bo, d_out);
}

// Round 2
// 413.108 us; speedup vs baseline: 1.5494x; 1.5494x over previous
//
#include <hip/hip_runtime.h>
#include <stdint.h>

#define DEV __device__ __forceinline__

typedef unsigned short u16;
typedef __bf16 bf16x8 __attribute__((ext_vector_type(8)));
typedef float  f32x4  __attribute__((ext_vector_type(4)));
typedef unsigned short u16x8 __attribute__((ext_vector_type(8)));
typedef unsigned short u16x4 __attribute__((ext_vector_type(4)));
typedef float  fvec4  __attribute__((ext_vector_type(4)));

constexpr int Sz   = 1024;  // sequence length
constexpr int Dm   = 1024;  // model dim
constexpr int HDm  = 64;    // head size
constexpr int NREL = 512;
constexpr int Mrows = 8192; // B*S

DEV u16 f2bf(float f) {
  uint32_t u = __builtin_bit_cast(uint32_t, f);
  uint32_t r = u + 0x7fffu + ((u >> 16) & 1u);
  return (u16)(r >> 16);
}
DEV float bf2f(u16 h) { return __builtin_bit_cast(float, (uint32_t)h << 16); }
DEV f32x4 mfma16(bf16x8 a, bf16x8 b, f32x4 c) {
  return __builtin_amdgcn_mfma_f32_16x16x32_bf16(a, b, c, 0, 0, 0);
}

// ---------------- fp32 -> bf16 conversion ----------------
__global__ __launch_bounds__(256) void cvt_kernel(const float* __restrict__ in,
                                                  u16* __restrict__ out) {
  size_t i = (size_t)blockIdx.x * 256 + threadIdx.x;
  fvec4 v = *(const fvec4*)(in + i * 4);
  u16x4 o;
  o[0] = f2bf(v[0]); o[1] = f2bf(v[1]); o[2] = f2bf(v[2]); o[3] = f2bf(v[3]);
  *(u16x4*)(out + i * 4) = o;
}

// ---------------- GEMM: C[m,n] = sum_k A[m,k]*Bw[n,k] + bias[n] ----------------
// XOR-swizzled LDS (16B granule ^ (row&7)) to kill stride-128B bank conflicts.
template<bool A_F32, bool OUT_BF16>
__global__ __launch_bounds__(256) void gemm_bt(const void* __restrict__ Ain,
                                               const u16* __restrict__ Bw,
                                               const float* __restrict__ bias,
                                               void* __restrict__ Cout) {
  constexpr int BK = 64;
  __shared__ u16 As[128 * BK];
  __shared__ u16 Bs[128 * BK];
  const int tid = threadIdx.x;
  const int wave = tid >> 6, lane = tid & 63;
  const int lr = lane & 15, lg = lane >> 4;
  const int m0 = blockIdx.y * 128, n0 = blockIdx.x * 128;
  const int wr = (wave >> 1) * 64, wc = (wave & 1) * 64;
  f32x4 acc[4][4] = {};
  for (int k0 = 0; k0 < Dm; k0 += BK) {
    // B tile: async global->LDS, source-swizzled so LDS[row][c16] = B[row][c16^(row&7)]
    #pragma unroll
    for (int it = 0; it < 4; ++it) {
      int chunk = it * 256 + wave * 64 + lane;
      int row = chunk >> 3, c16 = chunk & 7;
      const u16* src = Bw + (size_t)(n0 + row) * Dm + k0 + ((c16 ^ (row & 7)) * 8);
      __builtin_amdgcn_global_load_lds(
          (const __attribute__((address_space(1))) void*)src,
          (__attribute__((address_space(3))) void*)&Bs[(it * 256 + wave * 64) * 8],
          16, 0, 0);
    }
    if (A_F32) {
      const float* Af = (const float*)Ain;
      #pragma unroll
      for (int it = 0; it < 4; ++it) {
        int chunk = it * 256 + tid;
        int row = chunk >> 3, c16 = chunk & 7;
        const float* src = Af + (size_t)(m0 + row) * Dm + k0 + c16 * 8;
        fvec4 lo = *(const fvec4*)src;
        fvec4 hi = *(const fvec4*)(src + 4);
        u16x8 v;
        v[0] = f2bf(lo[0]); v[1] = f2bf(lo[1]); v[2] = f2bf(lo[2]); v[3] = f2bf(lo[3]);
        v[4] = f2bf(hi[0]); v[5] = f2bf(hi[1]); v[6] = f2bf(hi[2]); v[7] = f2bf(hi[3]);
        *(u16x8*)&As[row * 64 + ((c16 ^ (row & 7)) * 8)] = v;
      }
    } else {
      const u16* Ab = (const u16*)Ain;
      #pragma unroll
      for (int it = 0; it < 4; ++it) {
        int chunk = it * 256 + wave * 64 + lane;
        int row = chunk >> 3, c16 = chunk & 7;
        const u16* src = Ab + (size_t)(m0 + row) * Dm + k0 + ((c16 ^ (row & 7)) * 8);
        __builtin_amdgcn_global_load_lds(
            (const __attribute__((address_space(1))) void*)src,
            (__attribute__((address_space(3))) void*)&As[(it * 256 + wave * 64) * 8],
            16, 0, 0);
      }
    }
    __syncthreads();
    #pragma unroll
    for (int kk = 0; kk < 2; ++kk) {
      bf16x8 af[4], bf_[4];
      #pragma unroll
      for (int m = 0; m < 4; ++m)
        af[m] = *(const bf16x8*)&As[(wr + m * 16 + lr) * 64 + (((kk * 4 + lg) ^ (lr & 7)) * 8)];
      #pragma unroll
      for (int n = 0; n < 4; ++n)
        bf_[n] = *(const bf16x8*)&Bs[(wc + n * 16 + lr) * 64 + (((kk * 4 + lg) ^ (lr & 7)) * 8)];
      #pragma unroll
      for (int m = 0; m < 4; ++m)
        #pragma unroll
        for (int n = 0; n < 4; ++n)
          acc[m][n] = mfma16(af[m], bf_[n], acc[m][n]);
    }
    __syncthreads();
  }
  float bv[4];
  #pragma unroll
  for (int n = 0; n < 4; ++n) bv[n] = bias[n0 + wc + n * 16 + lr];
  #pragma unroll
  for (int m = 0; m < 4; ++m) {
    #pragma unroll
    for (int n = 0; n < 4; ++n) {
      const int gcol = n0 + wc + n * 16 + lr;
      #pragma unroll
      for (int r = 0; r < 4; ++r) {
        const int grow = m0 + wr + m * 16 + lg * 4 + r;
        float v = acc[m][n][r] + bv[n];
        if (OUT_BF16)
          ((u16*)Cout)[(size_t)grow * Dm + gcol] = f2bf(v);
        else
          ((float*)Cout)[(size_t)grow * Dm + gcol] = v;
      }
    }
  }
}

// ---------------- fused causal attention with relative-position bias ----------------
// 256 threads = 4 waves; block owns one (b,h) and 64 q rows (16 per wave).
// Windowed REL (width 79) rebuilt per KV tile via MFMA against bf16 pos table.
// LDS ~38 KB -> 4 blocks/CU.
__global__ __launch_bounds__(256, 4) void attn_kernel(const u16* __restrict__ Q,
                                                      const u16* __restrict__ Kb,
                                                      const u16* __restrict__ Vb,
                                                      const u16* __restrict__ posB,
                                                      u16* __restrict__ O) {
  __shared__ u16 RELW[4][16][88];  // per-wave REL window [qrow][w], w = rel - (wq-j0-63)
  __shared__ u16 Ks[64 * 64];      // K tile, XOR-swizzled granules
  __shared__ u16 Vt[64 * 72];      // V^T tile [d][j], stride 72
  __shared__ u16 Pw[4][16 * 72];   // per-wave P tile

  const int tid = threadIdx.x;
  const int wave = tid >> 6, lane = tid & 63;
  const int lr = lane & 15, lg = lane >> 4;
  const int bid = blockIdx.x;
  const int bh = bid >> 4;
  const int qi = 15 - (bid & 15);  // reversed: heavy blocks first
  const int b = bh >> 4, h = bh & 15;
  const int qb = qi * 64;
  const int wq = qb + wave * 16;

  const u16* qptr = Q + (size_t)(b * Sz + wq + lr) * Dm + h * HDm;
  bf16x8 qf[2];
  qf[0] = *(const bf16x8*)(qptr + lg * 8);
  qf[1] = *(const bf16x8*)(qptr + 32 + lg * 8);

  f32x4 oacc[4] = {};
  float m_i[4], l_i[4];
  #pragma unroll
  for (int r = 0; r < 4; ++r) { m_i[r] = -1e30f; l_i[r] = 0.f; }

  const int ntiles = qi + 1;
  for (int t = 0; t < ntiles; ++t) {
    const int j0 = t * 64;
    // ---- K tile: async global->LDS, source-swizzled ----
    #pragma unroll
    for (int it = 0; it < 2; ++it) {
      int chunk = it * 256 + wave * 64 + lane;
      int row = chunk >> 3, c16 = chunk & 7;
      const u16* src = Kb + (size_t)(b * Sz + j0 + row) * Dm + h * HDm + ((c16 ^ (row & 7)) * 8);
      __builtin_amdgcn_global_load_lds(
          (const __attribute__((address_space(1))) void*)src,
          (__attribute__((address_space(3))) void*)&Ks[(it * 256 + wave * 64) * 8],
          16, 0, 0);
    }
    // ---- V^T tile: lanes vary d by 1 -> conflict-free column stores ----
    #pragma unroll
    for (int it = 0; it < 4; ++it) {
      int row = it * 16 + (tid >> 4);
      int d0 = tid & 15;
      const u16* vsrc = Vb + (size_t)(b * Sz + j0 + row) * Dm + h * HDm + d0;
      #pragma unroll
      for (int s = 0; s < 4; ++s)
        Vt[(d0 + 16 * s) * 72 + row] = vsrc[16 * s];
    }
    // ---- windowed REL via MFMA (wave-private rows, no barrier needed) ----
    const int wb = wq - j0 - 63;
    #pragma unroll
    for (int wg = 0; wg < 5; ++wg) {
      int prow = wb + wg * 16 + lr;
      prow = prow < 0 ? 0 : (prow > NREL - 1 ? NREL - 1 : prow);
      const u16* pp = posB + prow * HDm;
      f32x4 acc = {};
      acc = mfma16(qf[0], *(const bf16x8*)(pp + lg * 8), acc);
      acc = mfma16(qf[1], *(const bf16x8*)(pp + 32 + lg * 8), acc);
      #pragma unroll
      for (int r = 0; r < 4; ++r)
        RELW[wave][lg * 4 + r][wg * 16 + lr] = f2bf(acc[r]);
    }
    __syncthreads();

    // ---- QK^T + bias gather + mask ----
    float p[4][4], tmax[4];
    #pragma unroll
    for (int r = 0; r < 4; ++r) tmax[r] = -3e38f;
    #pragma unroll
    for (int jg = 0; jg < 4; ++jg) {
      const int row = jg * 16 + lr;
      f32x4 a = {};
      a = mfma16(qf[0], *(const bf16x8*)&Ks[row * 64 + (((0 + lg) ^ (lr & 7)) * 8)], a);
      a = mfma16(qf[1], *(const bf16x8*)&Ks[row * 64 + (((4 + lg) ^ (lr & 7)) * 8)], a);
      #pragma unroll
      for (int r = 0; r < 4; ++r) {
        const int w = lg * 4 + r - jg * 16 - lr + 63;  // in [0,78]
        float bias = bf2f(RELW[wave][lg * 4 + r][w]);
        float s = (a[r] + bias) * 0.125f;
        if (j0 + row > wq + lg * 4 + r) s = -1e9f;  // causal mask
        p[r][jg] = s;
        tmax[r] = fmaxf(tmax[r], s);
      }
    }
    #pragma unroll
    for (int msk = 1; msk < 16; msk <<= 1)
      #pragma unroll
      for (int r = 0; r < 4; ++r)
        tmax[r] = fmaxf(tmax[r], __shfl_xor(tmax[r], msk, 64));

    float scale[4], lsum[4];
    #pragma unroll
    for (int r = 0; r < 4; ++r) {
      float mn = fmaxf(m_i[r], tmax[r]);
      scale[r] = __expf(m_i[r] - mn);
      m_i[r] = mn;
    }
    #pragma unroll
    for (int r = 0; r < 4; ++r) {
      float s0 = 0.f;
      #pragma unroll
      for (int jg = 0; jg < 4; ++jg) {
        p[r][jg] = __expf(p[r][jg] - m_i[r]);
        s0 += p[r][jg];
      }
      lsum[r] = s0;
    }
    #pragma unroll
    for (int msk = 1; msk < 16; msk <<= 1)
      #pragma unroll
      for (int r = 0; r < 4; ++r)
        lsum[r] += __shfl_xor(lsum[r], msk, 64);
    #pragma unroll
    for (int r = 0; r < 4; ++r) l_i[r] = l_i[r] * scale[r] + lsum[r];
    #pragma unroll
    for (int dg = 0; dg < 4; ++dg)
      #pragma unroll
      for (int r = 0; r < 4; ++r)
        oacc[dg][r] *= scale[r];

    // ---- P -> LDS (wave-private; within-wave LDS dep, no barrier) ----
    #pragma unroll
    for (int r = 0; r < 4; ++r)
      #pragma unroll
      for (int jg = 0; jg < 4; ++jg)
        Pw[wave][(lg * 4 + r) * 72 + jg * 16 + lr] = f2bf(p[r][jg]);

    // ---- PV ----
    #pragma unroll
    for (int kk = 0; kk < 2; ++kk) {
      bf16x8 pf = *(const bf16x8*)&Pw[wave][lr * 72 + kk * 32 + lg * 8];
      #pragma unroll
      for (int dg = 0; dg < 4; ++dg) {
        bf16x8 vf = *(const bf16x8*)&Vt[(dg * 16 + lr) * 72 + kk * 32 + lg * 8];
        oacc[dg] = mfma16(pf, vf, oacc[dg]);
      }
    }
    __syncthreads();
  }

  // epilogue: normalize, store bf16
  #pragma unroll
  for (int r = 0; r < 4; ++r) {
    float inv = 1.0f / l_i[r];
    size_t orow = (size_t)(b * Sz + wq + lg * 4 + r) * Dm + h * HDm;
    #pragma unroll
    for (int dg = 0; dg < 4; ++dg)
      O[orow + dg * 16 + lr] = f2bf(oacc[dg][r] * inv);
  }
}

// ---------------- launcher ----------------
extern "C" void kernel_launch(void* const* d_in, const int* in_sizes, int n_in,
                              void* d_out, int out_size, void* d_ws, size_t ws_size,
                              hipStream_t stream) {
  const float* query = (const float*)d_in[0];
  const float* key   = (const float*)d_in[1];
  const float* value = (const float*)d_in[2];
  const float* Wq    = (const float*)d_in[3];
  const float* bq    = (const float*)d_in[4];
  const float* Wk    = (const float*)d_in[5];
  const float* bk    = (const float*)d_in[6];
  const float* Wv    = (const float*)d_in[7];
  const float* bv    = (const float*)d_in[8];
  const float* Wo    = (const float*)d_in[9];
  const float* bo    = (const float*)d_in[10];
  const float* pos   = (const float*)d_in[11];

  char* ws = (char*)d_ws;
  u16*   WqB  = (u16*)(ws);
  u16*   WkB  = (u16*)(ws + (2ull << 20));
  u16*   WvB  = (u16*)(ws + (4ull << 20));
  u16*   WoB  = (u16*)(ws + (6ull << 20));
  u16*   posB = (u16*)(ws + (8ull << 20));
  u16*   Qb   = (u16*)(ws + (9ull << 20));
  u16*   Kb   = (u16*)(ws + (25ull << 20));
  u16*   Vb   = (u16*)(ws + (41ull << 20));
  u16*   Ob   = (u16*)(ws + (57ull << 20));

  cvt_kernel<<<1024, 256, 0, stream>>>(Wq, WqB);
  cvt_kernel<<<1024, 256, 0, stream>>>(Wk, WkB);
  cvt_kernel<<<1024, 256, 0, stream>>>(Wv, WvB);
  cvt_kernel<<<1024, 256, 0, stream>>>(Wo, WoB);
  cvt_kernel<<<32,   256, 0, stream>>>(pos, posB);

  dim3 ggrid(Dm / 128, Mrows / 128);
  gemm_bt<true, true><<<ggrid, 256, 0, stream>>>(query, WqB, bq, Qb);
  gemm_bt<true, true><<<ggrid, 256, 0, stream>>>(key,   WkB, bk, Kb);
  gemm_bt<true, true><<<ggrid, 256, 0, stream>>>(value, WvB, bv, Vb);

  attn_kernel<<<2048, 256, 0, stream>>>(Qb, Kb, Vb, posB, Ob);

  gemm_bt<false, false><<<ggrid, 256, 0, stream>>>(Ob, WoB, bo, d_out);
}

// Round 4
// 383.120 us; speedup vs baseline: 1.6707x; 1.0783x over previous
//
#include <hip/hip_runtime.h>
#include <stdint.h>

#define DEV __device__ __forceinline__

typedef unsigned short u16;
typedef __bf16 bf16x8 __attribute__((ext_vector_type(8)));
typedef float  f32x4  __attribute__((ext_vector_type(4)));
typedef unsigned short u16x8 __attribute__((ext_vector_type(8)));
typedef unsigned short u16x4 __attribute__((ext_vector_type(4)));
typedef float  fvec4  __attribute__((ext_vector_type(4)));

constexpr int Sz   = 1024;  // sequence length
constexpr int Dm   = 1024;  // model dim
constexpr int HDm  = 64;    // head size
constexpr int NREL = 512;
constexpr int Mrows = 8192; // B*S

DEV u16 f2bf(float f) {
  uint32_t u = __builtin_bit_cast(uint32_t, f);
  uint32_t r = u + 0x7fffu + ((u >> 16) & 1u);
  return (u16)(r >> 16);
}
DEV float bf2f(u16 h) { return __builtin_bit_cast(float, (uint32_t)h << 16); }
DEV f32x4 mfma16(bf16x8 a, bf16x8 b, f32x4 c) {
  return __builtin_amdgcn_mfma_f32_16x16x32_bf16(a, b, c, 0, 0, 0);
}

// hardware transpose read. Lane l fetches 8B at its OWN addr; fixed cross-lane
// permute within each 16-lane group delivers elem j = region[(l&15) + 16j],
// region = union of the group's fetches. Lane l must pass base + (l&15)*8B.
DEV u16x4 tr0(const u16* p) {
  u16x4 d;
  asm volatile("ds_read_b64_tr_b16 %0, %1"
               : "=v"(d)
               : "v"((const __attribute__((address_space(3))) u16*)p));
  return d;
}
DEV u16x4 tr512(const u16* p) {  // +512 bytes = next 4-row (j) subtile
  u16x4 d;
  asm volatile("ds_read_b64_tr_b16 %0, %1 offset:512"
               : "=v"(d)
               : "v"((const __attribute__((address_space(3))) u16*)p));
  return d;
}
DEV bf16x8 mk8(u16x4 a, u16x4 b) {
  u16x8 r;
  r[0] = a[0]; r[1] = a[1]; r[2] = a[2]; r[3] = a[3];
  r[4] = b[0]; r[5] = b[1]; r[6] = b[2]; r[7] = b[3];
  return __builtin_bit_cast(bf16x8, r);
}

// ---------------- fp32 -> bf16 conversion ----------------
__global__ __launch_bounds__(256) void cvt_kernel(const float* __restrict__ in,
                                                  u16* __restrict__ out) {
  size_t i = (size_t)blockIdx.x * 256 + threadIdx.x;
  fvec4 v = *(const fvec4*)(in + i * 4);
  u16x4 o;
  o[0] = f2bf(v[0]); o[1] = f2bf(v[1]); o[2] = f2bf(v[2]); o[3] = f2bf(v[3]);
  *(u16x4*)(out + i * 4) = o;
}

// ---------------- GEMM: C[m,n] = sum_k A[m,k]*Bw[n,k] + bias[n] ----------------
// Both operands bf16, both staged via global_load_lds with XOR-swizzled source.
template<bool OUT_BF16>
__global__ __launch_bounds__(256) void gemm_bt(const u16* __restrict__ A,
                                               const u16* __restrict__ Bw,
                                               const float* __restrict__ bias,
                                               void* __restrict__ Cout) {
  __shared__ u16 As[128 * 64];
  __shared__ u16 Bs[128 * 64];
  const int tid = threadIdx.x;
  const int wave = tid >> 6, lane = tid & 63;
  const int lr = lane & 15, lg = lane >> 4;
  const int m0 = blockIdx.y * 128, n0 = blockIdx.x * 128;
  const int wr = (wave >> 1) * 64, wc = (wave & 1) * 64;
  f32x4 acc[4][4] = {};
  for (int k0 = 0; k0 < Dm; k0 += 64) {
    #pragma unroll
    for (int it = 0; it < 4; ++it) {
      int chunk = it * 256 + wave * 64 + lane;
      int row = chunk >> 3, c16 = chunk & 7;
      const u16* bsrc = Bw + (size_t)(n0 + row) * Dm + k0 + ((c16 ^ (row & 7)) * 8);
      __builtin_amdgcn_global_load_lds(
          (const __attribute__((address_space(1))) void*)bsrc,
          (__attribute__((address_space(3))) void*)&Bs[(it * 256 + wave * 64) * 8],
          16, 0, 0);
      const u16* asrc = A + (size_t)(m0 + row) * Dm + k0 + ((c16 ^ (row & 7)) * 8);
      __builtin_amdgcn_global_load_lds(
          (const __attribute__((address_space(1))) void*)asrc,
          (__attribute__((address_space(3))) void*)&As[(it * 256 + wave * 64) * 8],
          16, 0, 0);
    }
    __syncthreads();
    #pragma unroll
    for (int kk = 0; kk < 2; ++kk) {
      bf16x8 af[4], bf_[4];
      #pragma unroll
      for (int m = 0; m < 4; ++m)
        af[m] = *(const bf16x8*)&As[(wr + m * 16 + lr) * 64 + (((kk * 4 + lg) ^ (lr & 7)) * 8)];
      #pragma unroll
      for (int n = 0; n < 4; ++n)
        bf_[n] = *(const bf16x8*)&Bs[(wc + n * 16 + lr) * 64 + (((kk * 4 + lg) ^ (lr & 7)) * 8)];
      #pragma unroll
      for (int m = 0; m < 4; ++m)
        #pragma unroll
        for (int n = 0; n < 4; ++n)
          acc[m][n] = mfma16(af[m], bf_[n], acc[m][n]);
    }
    __syncthreads();
  }
  float bv[4];
  #pragma unroll
  for (int n = 0; n < 4; ++n) bv[n] = bias[n0 + wc + n * 16 + lr];
  #pragma unroll
  for (int m = 0; m < 4; ++m) {
    #pragma unroll
    for (int n = 0; n < 4; ++n) {
      const int gcol = n0 + wc + n * 16 + lr;
      #pragma unroll
      for (int r = 0; r < 4; ++r) {
        const int grow = m0 + wr + m * 16 + lg * 4 + r;
        float v = acc[m][n][r] + bv[n];
        if (OUT_BF16)
          ((u16*)Cout)[(size_t)grow * Dm + gcol] = f2bf(v);
        else
          ((float*)Cout)[(size_t)grow * Dm + gcol] = v;
      }
    }
  }
}

// ---------------- fused causal attention with relative-position bias ----------------
// 512 threads = 8 waves; block owns one (b,h) and 128 q rows (16 per wave).
// K: global_load_lds + XOR source swizzle. V: global_load_lds into 4x16-subtiled
// layout (pre-swizzled source), consumed via ds_read_b64_tr_b16 in PV.
// RELW and P share one per-wave LDS region (disjoint in-wave live ranges).
__global__ __launch_bounds__(512, 8) void attn_kernel(const u16* __restrict__ Q,
                                                      const u16* __restrict__ Kb,
                                                      const u16* __restrict__ Vb,
                                                      const u16* __restrict__ posB,
                                                      u16* __restrict__ O) {
  __shared__ u16 Ks[64 * 64];     // K tile, XOR-swizzled 16B granules
  __shared__ u16 Vs[64 * 64];     // V tile subtiled [j>>2][d>>4][j&3][d&15]
  __shared__ u16 SH[8][16 * 88];  // per-wave: REL window [q][w] / P tile [q][j]

  const int tid = threadIdx.x;
  const int wave = tid >> 6, lane = tid & 63;
  const int lr = lane & 15, lg = lane >> 4;
  const int bid = blockIdx.x;
  const int bh = bid >> 3;
  const int k2 = (bid >> 8) & 3;
  // qi = (bid&7) XOR const(k2): bijective per (b,h); spreads heavy/light blocks
  const int qi = (bid & 7) ^ ((k2 & 1) * 7) ^ (((k2 >> 1) & 1) * 2);
  const int b = bh >> 4, h = bh & 15;
  const int qb = qi * 128;
  const int wq = qb + wave * 16;
  u16* SHW = SH[wave];

  const u16* qptr = Q + (size_t)(b * Sz + wq + lr) * Dm + h * HDm;
  bf16x8 qf[2];
  qf[0] = *(const bf16x8*)(qptr + lg * 8);
  qf[1] = *(const bf16x8*)(qptr + 32 + lg * 8);

  // staging source indices (one 16B chunk per thread per tile, slot = tid)
  const int krow = tid >> 3, kc = tid & 7;                  // K: row-major swizzled
  const int vj = (tid >> 5) * 4 + ((tid >> 1) & 3);         // V: subtile layout
  const int vd = ((tid >> 3) & 3) * 16 + (tid & 1) * 8;

  f32x4 oacc[4] = {};
  float m_i[4], l_i[4];
  #pragma unroll
  for (int r = 0; r < 4; ++r) { m_i[r] = -1e30f; l_i[r] = 0.f; }

  const int ntiles = 2 * qi + 2;
  for (int t = 0; t < ntiles; ++t) {
    const int j0 = t * 64;
    // ---- K & V tiles: one global_load_lds each per thread ----
    const u16* ksrc = Kb + (size_t)(b * Sz + j0 + krow) * Dm + h * HDm + ((kc ^ (krow & 7)) * 8);
    __builtin_amdgcn_global_load_lds(
        (const __attribute__((address_space(1))) void*)ksrc,
        (__attribute__((address_space(3))) void*)&Ks[wave * 512],
        16, 0, 0);
    const u16* vsrc = Vb + (size_t)(b * Sz + j0 + vj) * Dm + h * HDm + vd;
    __builtin_amdgcn_global_load_lds(
        (const __attribute__((address_space(1))) void*)vsrc,
        (__attribute__((address_space(3))) void*)&Vs[wave * 512],
        16, 0, 0);

    const bool active = (j0 <= wq + 15);
    if (active) {
      // ---- windowed REL via MFMA (wave-private rows) ----
      const int wb = wq - j0 - 63;
      #pragma unroll
      for (int wg = 0; wg < 5; ++wg) {
        int prow = wb + wg * 16 + lr;
        prow = prow < 0 ? 0 : (prow > NREL - 1 ? NREL - 1 : prow);
        const u16* pp = posB + prow * HDm;
        f32x4 acc = {};
        acc = mfma16(qf[0], *(const bf16x8*)(pp + lg * 8), acc);
        acc = mfma16(qf[1], *(const bf16x8*)(pp + 32 + lg * 8), acc);
        #pragma unroll
        for (int r = 0; r < 4; ++r)
          SHW[(lg * 4 + r) * 88 + wg * 16 + lr] = f2bf(acc[r]);
      }
    }
    __syncthreads();

    if (active) {
      // ---- QK^T + bias gather + mask ----
      float p[4][4], tmax[4];
      #pragma unroll
      for (int r = 0; r < 4; ++r) tmax[r] = -3e38f;
      #pragma unroll
      for (int jg = 0; jg < 4; ++jg) {
        const int row = jg * 16 + lr;
        f32x4 a = {};
        a = mfma16(qf[0], *(const bf16x8*)&Ks[row * 64 + (((0 + lg) ^ (lr & 7)) * 8)], a);
        a = mfma16(qf[1], *(const bf16x8*)&Ks[row * 64 + (((4 + lg) ^ (lr & 7)) * 8)], a);
        #pragma unroll
        for (int r = 0; r < 4; ++r) {
          const int w = lg * 4 + r - jg * 16 - lr + 63;  // in [0,78]
          float bias = bf2f(SHW[(lg * 4 + r) * 88 + w]);
          float s = (a[r] + bias) * 0.125f;
          if (j0 + row > wq + lg * 4 + r) s = -1e9f;
          p[r][jg] = s;
          tmax[r] = fmaxf(tmax[r], s);
        }
      }
      #pragma unroll
      for (int msk = 1; msk < 16; msk <<= 1)
        #pragma unroll
        for (int r = 0; r < 4; ++r)
          tmax[r] = fmaxf(tmax[r], __shfl_xor(tmax[r], msk, 64));

      float scale[4], lsum[4];
      #pragma unroll
      for (int r = 0; r < 4; ++r) {
        float mn = fmaxf(m_i[r], tmax[r]);
        scale[r] = __expf(m_i[r] - mn);
        m_i[r] = mn;
      }
      #pragma unroll
      for (int r = 0; r < 4; ++r) {
        float s0 = 0.f;
        #pragma unroll
        for (int jg = 0; jg < 4; ++jg) {
          p[r][jg] = __expf(p[r][jg] - m_i[r]);
          s0 += p[r][jg];
        }
        lsum[r] = s0;
      }
      #pragma unroll
      for (int msk = 1; msk < 16; msk <<= 1)
        #pragma unroll
        for (int r = 0; r < 4; ++r)
          lsum[r] += __shfl_xor(lsum[r], msk, 64);
      #pragma unroll
      for (int r = 0; r < 4; ++r) l_i[r] = l_i[r] * scale[r] + lsum[r];
      #pragma unroll
      for (int dg = 0; dg < 4; ++dg)
        #pragma unroll
        for (int r = 0; r < 4; ++r)
          oacc[dg][r] *= scale[r];

      // ---- P -> per-wave LDS region (overwrites REL window; no longer needed) ----
      #pragma unroll
      for (int r = 0; r < 4; ++r)
        #pragma unroll
        for (int jg = 0; jg < 4; ++jg)
          SHW[(lg * 4 + r) * 88 + jg * 16 + lr] = f2bf(p[r][jg]);

      // ---- PV: V fragments via hardware transpose read ----
      // lane lr of group lg passes subtile base + lr*8B; delivered elem j =
      // subtile[lr + 16j] = V[kk*32+lg*8+j][dg*16+lr].
      #pragma unroll
      for (int kk = 0; kk < 2; ++kk) {
        bf16x8 pf = *(const bf16x8*)&SHW[lr * 88 + kk * 32 + lg * 8];
        u16x4 va[4][2];
        const int t0 = kk * 8 + lg * 2;
        #pragma unroll
        for (int dg = 0; dg < 4; ++dg) {
          const u16* base = &Vs[t0 * 256 + dg * 64 + lr * 4];
          va[dg][0] = tr0(base);
          va[dg][1] = tr512(base);
        }
        asm volatile("s_waitcnt lgkmcnt(0)" ::: "memory");
        __builtin_amdgcn_sched_barrier(0);
        #pragma unroll
        for (int dg = 0; dg < 4; ++dg)
          oacc[dg] = mfma16(pf, mk8(va[dg][0], va[dg][1]), oacc[dg]);
      }
    }
    __syncthreads();
  }

  // epilogue: normalize, store bf16
  #pragma unroll
  for (int r = 0; r < 4; ++r) {
    float inv = 1.0f / l_i[r];
    size_t orow = (size_t)(b * Sz + wq + lg * 4 + r) * Dm + h * HDm;
    #pragma unroll
    for (int dg = 0; dg < 4; ++dg)
      O[orow + dg * 16 + lr] = f2bf(oacc[dg][r] * inv);
  }
}

// ---------------- launcher ----------------
extern "C" void kernel_launch(void* const* d_in, const int* in_sizes, int n_in,
                              void* d_out, int out_size, void* d_ws, size_t ws_size,
                              hipStream_t stream) {
  const float* query = (const float*)d_in[0];
  const float* key   = (const float*)d_in[1];
  const float* value = (const float*)d_in[2];
  const float* Wq    = (const float*)d_in[3];
  const float* bq    = (const float*)d_in[4];
  const float* Wk    = (const float*)d_in[5];
  const float* bk    = (const float*)d_in[6];
  const float* Wv    = (const float*)d_in[7];
  const float* bv    = (const float*)d_in[8];
  const float* Wo    = (const float*)d_in[9];
  const float* bo    = (const float*)d_in[10];
  const float* pos   = (const float*)d_in[11];

  char* ws = (char*)d_ws;
  u16* WqB  = (u16*)(ws);                 // 2 MB
  u16* WkB  = (u16*)(ws + (2ull << 20));  // 2 MB
  u16* WvB  = (u16*)(ws + (4ull << 20));  // 2 MB
  u16* WoB  = (u16*)(ws + (6ull << 20));  // 2 MB
  u16* posB = (u16*)(ws + (8ull << 20));  // 64 KB
  u16* Xq   = (u16*)(ws + (9ull << 20));  // 16 MB (reused as Ob)
  u16* Xk   = (u16*)(ws + (25ull << 20)); // 16 MB (reused as Vb)
  u16* Xv   = (u16*)(ws + (41ull << 20)); // 16 MB
  u16* Qb   = (u16*)(ws + (57ull << 20)); // 16 MB
  u16* Kb   = (u16*)(ws + (73ull << 20)); // 16 MB
  u16* Vb   = Xk;                         // Xk dead after K projection
  u16* Ob   = Xq;                         // Xq dead after Q projection

  cvt_kernel<<<1024, 256, 0, stream>>>(Wq, WqB);
  cvt_kernel<<<1024, 256, 0, stream>>>(Wk, WkB);
  cvt_kernel<<<1024, 256, 0, stream>>>(Wv, WvB);
  cvt_kernel<<<1024, 256, 0, stream>>>(Wo, WoB);
  cvt_kernel<<<32,   256, 0, stream>>>(pos, posB);
  cvt_kernel<<<8192, 256, 0, stream>>>(query, Xq);
  cvt_kernel<<<8192, 256, 0, stream>>>(key,   Xk);
  cvt_kernel<<<8192, 256, 0, stream>>>(value, Xv);

  dim3 ggrid(Dm / 128, Mrows / 128);
  gemm_bt<true><<<ggrid, 256, 0, stream>>>(Xq, WqB, bq, Qb);
  gemm_bt<true><<<ggrid, 256, 0, stream>>>(Xk, WkB, bk, Kb);
  gemm_bt<true><<<ggrid, 256, 0, stream>>>(Xv, WvB, bv, Vb);

  attn_kernel<<<1024, 512, 0, stream>>>(Qb, Kb, Vb, posB, Ob);

  gemm_bt<false><<<ggrid, 256, 0, stream>>>(Ob, WoB, bo, d_out);
}

// Round 5
// 290.601 us; speedup vs baseline: 2.2026x; 1.3184x over previous
//
#include <hip/hip_runtime.h>
#include <stdint.h>

#define DEV __device__ __forceinline__

typedef unsigned short u16;
typedef __bf16 bf16x8 __attribute__((ext_vector_type(8)));
typedef float  f32x4  __attribute__((ext_vector_type(4)));
typedef unsigned short u16x8 __attribute__((ext_vector_type(8)));
typedef unsigned short u16x4 __attribute__((ext_vector_type(4)));
typedef float  fvec4  __attribute__((ext_vector_type(4)));

constexpr int Sz   = 1024;  // sequence length
constexpr int Dm   = 1024;  // model dim
constexpr int HDm  = 64;    // head size
constexpr int NREL = 512;
constexpr int Mrows = 8192; // B*S

DEV u16 f2bf(float f) {
  uint32_t u = __builtin_bit_cast(uint32_t, f);
  uint32_t r = u + 0x7fffu + ((u >> 16) & 1u);
  return (u16)(r >> 16);
}
DEV float bf2f(u16 h) { return __builtin_bit_cast(float, (uint32_t)h << 16); }
DEV f32x4 mfma16(bf16x8 a, bf16x8 b, f32x4 c) {
  return __builtin_amdgcn_mfma_f32_16x16x32_bf16(a, b, c, 0, 0, 0);
}

// hardware transpose read. Lane l fetches 8B at its OWN addr; fixed cross-lane
// permute within each 16-lane group delivers elem j = region[(l&15) + 16j],
// region = union of the group's fetches. Lane l must pass base + (l&15)*8B.
DEV u16x4 tr0(const u16* p) {
  u16x4 d;
  asm volatile("ds_read_b64_tr_b16 %0, %1"
               : "=v"(d)
               : "v"((const __attribute__((address_space(3))) u16*)p));
  return d;
}
DEV u16x4 tr512(const u16* p) {  // +512 bytes = next 4-row (j) subtile
  u16x4 d;
  asm volatile("ds_read_b64_tr_b16 %0, %1 offset:512"
               : "=v"(d)
               : "v"((const __attribute__((address_space(3))) u16*)p));
  return d;
}
DEV bf16x8 mk8(u16x4 a, u16x4 b) {
  u16x8 r;
  r[0] = a[0]; r[1] = a[1]; r[2] = a[2]; r[3] = a[3];
  r[4] = b[0]; r[5] = b[1]; r[6] = b[2]; r[7] = b[3];
  return __builtin_bit_cast(bf16x8, r);
}

// ---------------- fp32 -> bf16 conversion ----------------
__global__ __launch_bounds__(256) void cvt_kernel(const float* __restrict__ in,
                                                  u16* __restrict__ out) {
  size_t i = (size_t)blockIdx.x * 256 + threadIdx.x;
  fvec4 v = *(const fvec4*)(in + i * 4);
  u16x4 o;
  o[0] = f2bf(v[0]); o[1] = f2bf(v[1]); o[2] = f2bf(v[2]); o[3] = f2bf(v[3]);
  *(u16x4*)(out + i * 4) = o;
}

// ---------------- GEMM: C[m,n] = sum_k A[m,k]*Bw[n,k] + bias[n] ----------------
// Both operands bf16, both staged via global_load_lds with XOR-swizzled source.
template<bool OUT_BF16>
__global__ __launch_bounds__(256) void gemm_bt(const u16* __restrict__ A,
                                               const u16* __restrict__ Bw,
                                               const float* __restrict__ bias,
                                               void* __restrict__ Cout) {
  __shared__ u16 As[128 * 64];
  __shared__ u16 Bs[128 * 64];
  const int tid = threadIdx.x;
  const int wave = tid >> 6, lane = tid & 63;
  const int lr = lane & 15, lg = lane >> 4;
  const int m0 = blockIdx.y * 128, n0 = blockIdx.x * 128;
  const int wr = (wave >> 1) * 64, wc = (wave & 1) * 64;
  f32x4 acc[4][4] = {};
  for (int k0 = 0; k0 < Dm; k0 += 64) {
    #pragma unroll
    for (int it = 0; it < 4; ++it) {
      int chunk = it * 256 + wave * 64 + lane;
      int row = chunk >> 3, c16 = chunk & 7;
      const u16* bsrc = Bw + (size_t)(n0 + row) * Dm + k0 + ((c16 ^ (row & 7)) * 8);
      __builtin_amdgcn_global_load_lds(
          (const __attribute__((address_space(1))) void*)bsrc,
          (__attribute__((address_space(3))) void*)&Bs[(it * 256 + wave * 64) * 8],
          16, 0, 0);
      const u16* asrc = A + (size_t)(m0 + row) * Dm + k0 + ((c16 ^ (row & 7)) * 8);
      __builtin_amdgcn_global_load_lds(
          (const __attribute__((address_space(1))) void*)asrc,
          (__attribute__((address_space(3))) void*)&As[(it * 256 + wave * 64) * 8],
          16, 0, 0);
    }
    __syncthreads();
    #pragma unroll
    for (int kk = 0; kk < 2; ++kk) {
      bf16x8 af[4], bf_[4];
      #pragma unroll
      for (int m = 0; m < 4; ++m)
        af[m] = *(const bf16x8*)&As[(wr + m * 16 + lr) * 64 + (((kk * 4 + lg) ^ (lr & 7)) * 8)];
      #pragma unroll
      for (int n = 0; n < 4; ++n)
        bf_[n] = *(const bf16x8*)&Bs[(wc + n * 16 + lr) * 64 + (((kk * 4 + lg) ^ (lr & 7)) * 8)];
      #pragma unroll
      for (int m = 0; m < 4; ++m)
        #pragma unroll
        for (int n = 0; n < 4; ++n)
          acc[m][n] = mfma16(af[m], bf_[n], acc[m][n]);
    }
    __syncthreads();
  }
  float bv[4];
  #pragma unroll
  for (int n = 0; n < 4; ++n) bv[n] = bias[n0 + wc + n * 16 + lr];
  #pragma unroll
  for (int m = 0; m < 4; ++m) {
    #pragma unroll
    for (int n = 0; n < 4; ++n) {
      const int gcol = n0 + wc + n * 16 + lr;
      #pragma unroll
      for (int r = 0; r < 4; ++r) {
        const int grow = m0 + wr + m * 16 + lg * 4 + r;
        float v = acc[m][n][r] + bv[n];
        if (OUT_BF16)
          ((u16*)Cout)[(size_t)grow * Dm + gcol] = f2bf(v);
        else
          ((float*)Cout)[(size_t)grow * Dm + gcol] = v;
      }
    }
  }
}

// ---------------- fused causal attention with relative-position bias ----------------
// 512 threads = 8 waves; block owns one (b,h) and 128 q rows (16 per wave).
// K: global_load_lds + XOR source swizzle. V: global_load_lds into 4x16-subtiled
// layout (pre-swizzled source), consumed via ds_read_b64_tr_b16 in PV.
// RELW and P share one per-wave LDS region (disjoint in-wave live ranges).
// launch_bounds (512,4): VGPR cap 128 -> NO scratch spill (8 waves/EU spilled).
__global__ __launch_bounds__(512, 4) void attn_kernel(const u16* __restrict__ Q,
                                                      const u16* __restrict__ Kb,
                                                      const u16* __restrict__ Vb,
                                                      const u16* __restrict__ posB,
                                                      u16* __restrict__ O) {
  __shared__ u16 Ks[64 * 64];     // K tile, XOR-swizzled 16B granules
  __shared__ u16 Vs[64 * 64];     // V tile subtiled [j>>2][d>>4][j&3][d&15]
  __shared__ u16 SH[8][16 * 88];  // per-wave: REL window [q][w] / P tile [q][j]

  const int tid = threadIdx.x;
  const int wave = tid >> 6, lane = tid & 63;
  const int lr = lane & 15, lg = lane >> 4;
  // XCD-clustered mapping: consecutive bids round-robin XCDs, so give each
  // XCD a fixed set of 16 (b,h) pairs (4 MB K/V = one XCD L2) and iterate
  // their q-blocks over time; qi XOR bh_local spreads heavy/light blocks.
  const int bid = blockIdx.x;
  const int xcd = bid & 7;
  const int p   = bid >> 3;
  const int bhl = p & 15;
  const int bh  = xcd * 16 + bhl;
  const int qi  = (p >> 4) ^ (bhl & 7);
  const int b = bh >> 4, h = bh & 15;
  const int qb = qi * 128;
  const int wq = qb + wave * 16;
  u16* SHW = SH[wave];

  const u16* qptr = Q + (size_t)(b * Sz + wq + lr) * Dm + h * HDm;
  bf16x8 qf[2];
  qf[0] = *(const bf16x8*)(qptr + lg * 8);
  qf[1] = *(const bf16x8*)(qptr + 32 + lg * 8);

  // staging source indices (one 16B chunk per thread per tile, slot = tid)
  const int krow = tid >> 3, kc = tid & 7;                  // K: row-major swizzled
  const int vj = (tid >> 5) * 4 + ((tid >> 1) & 3);         // V: subtile layout
  const int vd = ((tid >> 3) & 3) * 16 + (tid & 1) * 8;

  f32x4 oacc[4] = {};
  float m_i[4], l_i[4];
  #pragma unroll
  for (int r = 0; r < 4; ++r) { m_i[r] = -1e30f; l_i[r] = 0.f; }

  const int ntiles = 2 * qi + 2;
  for (int t = 0; t < ntiles; ++t) {
    const int j0 = t * 64;
    // ---- K & V tiles: one global_load_lds each per thread ----
    const u16* ksrc = Kb + (size_t)(b * Sz + j0 + krow) * Dm + h * HDm + ((kc ^ (krow & 7)) * 8);
    __builtin_amdgcn_global_load_lds(
        (const __attribute__((address_space(1))) void*)ksrc,
        (__attribute__((address_space(3))) void*)&Ks[wave * 512],
        16, 0, 0);
    const u16* vsrc = Vb + (size_t)(b * Sz + j0 + vj) * Dm + h * HDm + vd;
    __builtin_amdgcn_global_load_lds(
        (const __attribute__((address_space(1))) void*)vsrc,
        (__attribute__((address_space(3))) void*)&Vs[wave * 512],
        16, 0, 0);

    const bool active = (j0 <= wq + 15);
    if (active) {
      // ---- windowed REL via MFMA (wave-private rows) ----
      const int wb = wq - j0 - 63;
      #pragma unroll
      for (int wg = 0; wg < 5; ++wg) {
        int prow = wb + wg * 16 + lr;
        prow = prow < 0 ? 0 : (prow > NREL - 1 ? NREL - 1 : prow);
        const u16* pp = posB + prow * HDm;
        f32x4 acc = {};
        acc = mfma16(qf[0], *(const bf16x8*)(pp + lg * 8), acc);
        acc = mfma16(qf[1], *(const bf16x8*)(pp + 32 + lg * 8), acc);
        #pragma unroll
        for (int r = 0; r < 4; ++r)
          SHW[(lg * 4 + r) * 88 + wg * 16 + lr] = f2bf(acc[r]);
      }
    }
    __syncthreads();

    if (active) {
      // ---- QK^T + bias gather + mask ----
      float p_[4][4], tmax[4];
      #pragma unroll
      for (int r = 0; r < 4; ++r) tmax[r] = -3e38f;
      #pragma unroll
      for (int jg = 0; jg < 4; ++jg) {
        const int row = jg * 16 + lr;
        f32x4 a = {};
        a = mfma16(qf[0], *(const bf16x8*)&Ks[row * 64 + (((0 + lg) ^ (lr & 7)) * 8)], a);
        a = mfma16(qf[1], *(const bf16x8*)&Ks[row * 64 + (((4 + lg) ^ (lr & 7)) * 8)], a);
        #pragma unroll
        for (int r = 0; r < 4; ++r) {
          const int w = lg * 4 + r - jg * 16 - lr + 63;  // in [0,78]
          float bias = bf2f(SHW[(lg * 4 + r) * 88 + w]);
          float s = (a[r] + bias) * 0.125f;
          if (j0 + row > wq + lg * 4 + r) s = -1e9f;
          p_[r][jg] = s;
          tmax[r] = fmaxf(tmax[r], s);
        }
      }
      #pragma unroll
      for (int msk = 1; msk < 16; msk <<= 1)
        #pragma unroll
        for (int r = 0; r < 4; ++r)
          tmax[r] = fmaxf(tmax[r], __shfl_xor(tmax[r], msk, 64));

      float scale[4], lsum[4];
      #pragma unroll
      for (int r = 0; r < 4; ++r) {
        float mn = fmaxf(m_i[r], tmax[r]);
        scale[r] = __expf(m_i[r] - mn);
        m_i[r] = mn;
      }
      #pragma unroll
      for (int r = 0; r < 4; ++r) {
        float s0 = 0.f;
        #pragma unroll
        for (int jg = 0; jg < 4; ++jg) {
          p_[r][jg] = __expf(p_[r][jg] - m_i[r]);
          s0 += p_[r][jg];
        }
        lsum[r] = s0;
      }
      #pragma unroll
      for (int msk = 1; msk < 16; msk <<= 1)
        #pragma unroll
        for (int r = 0; r < 4; ++r)
          lsum[r] += __shfl_xor(lsum[r], msk, 64);
      #pragma unroll
      for (int r = 0; r < 4; ++r) l_i[r] = l_i[r] * scale[r] + lsum[r];
      #pragma unroll
      for (int dg = 0; dg < 4; ++dg)
        #pragma unroll
        for (int r = 0; r < 4; ++r)
          oacc[dg][r] *= scale[r];

      // ---- P -> per-wave LDS region (overwrites REL window; no longer needed) ----
      #pragma unroll
      for (int r = 0; r < 4; ++r)
        #pragma unroll
        for (int jg = 0; jg < 4; ++jg)
          SHW[(lg * 4 + r) * 88 + jg * 16 + lr] = f2bf(p_[r][jg]);

      // ---- PV: V fragments via hardware transpose read ----
      // lane lr of group lg passes subtile base + lr*8B; delivered elem j =
      // subtile[lr + 16j] = V[kk*32+lg*8+j][dg*16+lr].
      #pragma unroll
      for (int kk = 0; kk < 2; ++kk) {
        bf16x8 pf = *(const bf16x8*)&SHW[lr * 88 + kk * 32 + lg * 8];
        u16x4 va[4][2];
        const int t0 = kk * 8 + lg * 2;
        #pragma unroll
        for (int dg = 0; dg < 4; ++dg) {
          const u16* base = &Vs[t0 * 256 + dg * 64 + lr * 4];
          va[dg][0] = tr0(base);
          va[dg][1] = tr512(base);
        }
        asm volatile("s_waitcnt lgkmcnt(0)" ::: "memory");
        __builtin_amdgcn_sched_barrier(0);
        #pragma unroll
        for (int dg = 0; dg < 4; ++dg)
          oacc[dg] = mfma16(pf, mk8(va[dg][0], va[dg][1]), oacc[dg]);
      }
    }
    __syncthreads();
  }

  // epilogue: normalize, store bf16
  #pragma unroll
  for (int r = 0; r < 4; ++r) {
    float inv = 1.0f / l_i[r];
    size_t orow = (size_t)(b * Sz + wq + lg * 4 + r) * Dm + h * HDm;
    #pragma unroll
    for (int dg = 0; dg < 4; ++dg)
      O[orow + dg * 16 + lr] = f2bf(oacc[dg][r] * inv);
  }
}

// ---------------- launcher ----------------
extern "C" void kernel_launch(void* const* d_in, const int* in_sizes, int n_in,
                              void* d_out, int out_size, void* d_ws, size_t ws_size,
                              hipStream_t stream) {
  const float* query = (const float*)d_in[0];
  const float* key   = (const float*)d_in[1];
  const float* value = (const float*)d_in[2];
  const float* Wq    = (const float*)d_in[3];
  const float* bq    = (const float*)d_in[4];
  const float* Wk    = (const float*)d_in[5];
  const float* bk    = (const float*)d_in[6];
  const float* Wv    = (const float*)d_in[7];
  const float* bv    = (const float*)d_in[8];
  const float* Wo    = (const float*)d_in[9];
  const float* bo    = (const float*)d_in[10];
  const float* pos   = (const float*)d_in[11];

  char* ws = (char*)d_ws;
  u16* WqB  = (u16*)(ws);                 // 2 MB
  u16* WkB  = (u16*)(ws + (2ull << 20));  // 2 MB
  u16* WvB  = (u16*)(ws + (4ull << 20));  // 2 MB
  u16* WoB  = (u16*)(ws + (6ull << 20));  // 2 MB
  u16* posB = (u16*)(ws + (8ull << 20));  // 64 KB
  u16* Xq   = (u16*)(ws + (9ull << 20));  // 16 MB (reused as Ob)
  u16* Xk   = (u16*)(ws + (25ull << 20)); // 16 MB (reused as Vb)
  u16* Xv   = (u16*)(ws + (41ull << 20)); // 16 MB
  u16* Qb   = (u16*)(ws + (57ull << 20)); // 16 MB
  u16* Kb   = (u16*)(ws + (73ull << 20)); // 16 MB
  u16* Vb   = Xk;                         // Xk dead after K projection
  u16* Ob   = Xq;                         // Xq dead after Q projection

  cvt_kernel<<<1024, 256, 0, stream>>>(Wq, WqB);
  cvt_kernel<<<1024, 256, 0, stream>>>(Wk, WkB);
  cvt_kernel<<<1024, 256, 0, stream>>>(Wv, WvB);
  cvt_kernel<<<1024, 256, 0, stream>>>(Wo, WoB);
  cvt_kernel<<<32,   256, 0, stream>>>(pos, posB);
  cvt_kernel<<<8192, 256, 0, stream>>>(query, Xq);
  cvt_kernel<<<8192, 256, 0, stream>>>(key,   Xk);
  cvt_kernel<<<8192, 256, 0, stream>>>(value, Xv);

  dim3 ggrid(Dm / 128, Mrows / 128);
  gemm_bt<true><<<ggrid, 256, 0, stream>>>(Xq, WqB, bq, Qb);
  gemm_bt<true><<<ggrid, 256, 0, stream>>>(Xk, WkB, bk, Kb);
  gemm_bt<true><<<ggrid, 256, 0, stream>>>(Xv, WvB, bv, Vb);

  attn_kernel<<<1024, 512, 0, stream>>>(Qb, Kb, Vb, posB, Ob);

  gemm_bt<false><<<ggrid, 256, 0, stream>>>(Ob, WoB, bo, d_out);
}

// Round 6
// 263.147 us; speedup vs baseline: 2.4324x; 1.1043x over previous
//
#include <hip/hip_runtime.h>
#include <stdint.h>

#define DEV __device__ __forceinline__

typedef unsigned short u16;
typedef __bf16 bf16x8 __attribute__((ext_vector_type(8)));
typedef float  f32x4  __attribute__((ext_vector_type(4)));
typedef unsigned short u16x8 __attribute__((ext_vector_type(8)));
typedef unsigned short u16x4 __attribute__((ext_vector_type(4)));
typedef float  fvec4  __attribute__((ext_vector_type(4)));

constexpr int Sz   = 1024;  // sequence length
constexpr int Dm   = 1024;  // model dim
constexpr int HDm  = 64;    // head size
constexpr int NREL = 512;
constexpr int Mrows = 8192; // B*S

DEV u16 f2bf(float f) {
  uint32_t u = __builtin_bit_cast(uint32_t, f);
  uint32_t r = u + 0x7fffu + ((u >> 16) & 1u);
  return (u16)(r >> 16);
}
DEV float bf2f(u16 h) { return __builtin_bit_cast(float, (uint32_t)h << 16); }
DEV f32x4 mfma16(bf16x8 a, bf16x8 b, f32x4 c) {
  return __builtin_amdgcn_mfma_f32_16x16x32_bf16(a, b, c, 0, 0, 0);
}

// hardware transpose read. Lane l fetches 8B at its OWN addr; fixed cross-lane
// permute within each 16-lane group delivers elem j = region[(l&15) + 16j].
DEV u16x4 tr0(const u16* p) {
  u16x4 d;
  asm volatile("ds_read_b64_tr_b16 %0, %1"
               : "=v"(d)
               : "v"((const __attribute__((address_space(3))) u16*)p));
  return d;
}
DEV u16x4 tr512(const u16* p) {  // +512 bytes = next 4-row (j) subtile
  u16x4 d;
  asm volatile("ds_read_b64_tr_b16 %0, %1 offset:512"
               : "=v"(d)
               : "v"((const __attribute__((address_space(3))) u16*)p));
  return d;
}
DEV bf16x8 mk8(u16x4 a, u16x4 b) {
  u16x8 r;
  r[0] = a[0]; r[1] = a[1]; r[2] = a[2]; r[3] = a[3];
  r[4] = b[0]; r[5] = b[1]; r[6] = b[2]; r[7] = b[3];
  return __builtin_bit_cast(bf16x8, r);
}

// ---------------- fp32 -> bf16 conversion ----------------
__global__ __launch_bounds__(256) void cvt_kernel(const float* __restrict__ in,
                                                  u16* __restrict__ out) {
  size_t i = (size_t)blockIdx.x * 256 + threadIdx.x;
  fvec4 v = *(const fvec4*)(in + i * 4);
  u16x4 o;
  o[0] = f2bf(v[0]); o[1] = f2bf(v[1]); o[2] = f2bf(v[2]); o[3] = f2bf(v[3]);
  *(u16x4*)(out + i * 4) = o;
}

// ---------------- GEMM: C[m,n] = sum_k A[m,k]*Bw[n,k] + bias[n] ----------------
template<bool OUT_BF16>
__global__ __launch_bounds__(256) void gemm_bt(const u16* __restrict__ A,
                                               const u16* __restrict__ Bw,
                                               const float* __restrict__ bias,
                                               void* __restrict__ Cout) {
  __shared__ u16 As[128 * 64];
  __shared__ u16 Bs[128 * 64];
  const int tid = threadIdx.x;
  const int wave = tid >> 6, lane = tid & 63;
  const int lr = lane & 15, lg = lane >> 4;
  const int m0 = blockIdx.y * 128, n0 = blockIdx.x * 128;
  const int wr = (wave >> 1) * 64, wc = (wave & 1) * 64;
  f32x4 acc[4][4] = {};
  for (int k0 = 0; k0 < Dm; k0 += 64) {
    #pragma unroll
    for (int it = 0; it < 4; ++it) {
      int chunk = it * 256 + wave * 64 + lane;
      int row = chunk >> 3, c16 = chunk & 7;
      const u16* bsrc = Bw + (size_t)(n0 + row) * Dm + k0 + ((c16 ^ (row & 7)) * 8);
      __builtin_amdgcn_global_load_lds(
          (const __attribute__((address_space(1))) void*)bsrc,
          (__attribute__((address_space(3))) void*)&Bs[(it * 256 + wave * 64) * 8],
          16, 0, 0);
      const u16* asrc = A + (size_t)(m0 + row) * Dm + k0 + ((c16 ^ (row & 7)) * 8);
      __builtin_amdgcn_global_load_lds(
          (const __attribute__((address_space(1))) void*)asrc,
          (__attribute__((address_space(3))) void*)&As[(it * 256 + wave * 64) * 8],
          16, 0, 0);
    }
    __syncthreads();
    #pragma unroll
    for (int kk = 0; kk < 2; ++kk) {
      bf16x8 af[4], bf_[4];
      #pragma unroll
      for (int m = 0; m < 4; ++m)
        af[m] = *(const bf16x8*)&As[(wr + m * 16 + lr) * 64 + (((kk * 4 + lg) ^ (lr & 7)) * 8)];
      #pragma unroll
      for (int n = 0; n < 4; ++n)
        bf_[n] = *(const bf16x8*)&Bs[(wc + n * 16 + lr) * 64 + (((kk * 4 + lg) ^ (lr & 7)) * 8)];
      #pragma unroll
      for (int m = 0; m < 4; ++m)
        #pragma unroll
        for (int n = 0; n < 4; ++n)
          acc[m][n] = mfma16(af[m], bf_[n], acc[m][n]);
    }
    __syncthreads();
  }
  float bv[4];
  #pragma unroll
  for (int n = 0; n < 4; ++n) bv[n] = bias[n0 + wc + n * 16 + lr];
  #pragma unroll
  for (int m = 0; m < 4; ++m) {
    #pragma unroll
    for (int n = 0; n < 4; ++n) {
      const int gcol = n0 + wc + n * 16 + lr;
      #pragma unroll
      for (int r = 0; r < 4; ++r) {
        const int grow = m0 + wr + m * 16 + lg * 4 + r;
        float v = acc[m][n][r] + bv[n];
        if (OUT_BF16)
          ((u16*)Cout)[(size_t)grow * Dm + gcol] = f2bf(v);
        else
          ((float*)Cout)[(size_t)grow * Dm + gcol] = v;
      }
    }
  }
}

// ---------------- fused causal attention with relative-position bias ----------------
// 512 blocks x 512 threads (8 waves). Each block: one (b,h), TWO q-chunk jobs
// (qi, 7-qi) -> uniform 18 tiles/block (no drain tail). K/V double-buffered
// with counted vmcnt(2) so prefetch stays in flight across barriers.
__global__ __launch_bounds__(512, 4) void attn_kernel(const u16* __restrict__ Q,
                                                      const u16* __restrict__ Kb,
                                                      const u16* __restrict__ Vb,
                                                      const u16* __restrict__ posB,
                                                      u16* __restrict__ O) {
  __shared__ u16 Ks[2][64 * 64];  // K tiles, XOR-swizzled 16B granules
  __shared__ u16 Vs[2][64 * 64];  // V tiles subtiled [j>>2][d>>4][j&3][d&15]
  __shared__ u16 SH[8][16 * 88];  // per-wave: REL window [q][w] / P tile [q][j]

  const int tid = threadIdx.x;
  const int wave = tid >> 6, lane = tid & 63;
  const int lr = lane & 15, lg = lane >> 4;
  // XCD-clustered: each XCD owns 16 (b,h) pairs (4 MB K/V = one L2).
  const int bid = blockIdx.x;
  const int xcd = bid & 7;
  const int idx = bid >> 3;        // 0..63
  const int bhl = idx & 15;
  const int pr  = idx >> 4;        // 0..3 -> job pair (pr, 7-pr)
  const int bh  = xcd * 16 + bhl;
  const int b = bh >> 4, h = bh & 15;
  const int nt0 = 2 * pr + 2;
  u16* SHW = SH[wave];

  // staging source indices (one 16B chunk per thread per tile, slot = tid)
  const int krow = tid >> 3, kc = tid & 7;            // K: row-major swizzled
  const int vj = (tid >> 5) * 4 + ((tid >> 1) & 3);   // V: subtile layout
  const int vd = ((tid >> 3) & 3) * 16 + (tid & 1) * 8;

  auto issue = [&](int u) {
    const int tt = (u >= nt0) ? (u - nt0) : u;
    const int j0 = tt * 64;
    const int bsel = u & 1;
    const u16* ksrc = Kb + (size_t)(b * Sz + j0 + krow) * Dm + h * HDm + ((kc ^ (krow & 7)) * 8);
    __builtin_amdgcn_global_load_lds(
        (const __attribute__((address_space(1))) void*)ksrc,
        (__attribute__((address_space(3))) void*)&Ks[bsel][wave * 512],
        16, 0, 0);
    const u16* vsrc = Vb + (size_t)(b * Sz + j0 + vj) * Dm + h * HDm + vd;
    __builtin_amdgcn_global_load_lds(
        (const __attribute__((address_space(1))) void*)vsrc,
        (__attribute__((address_space(3))) void*)&Vs[bsel][wave * 512],
        16, 0, 0);
  };

  issue(0);

  int u = 0;
  int qi = pr;
  for (int job = 0; job < 2; ++job) {
    const int qb = qi * 128;
    const int wq = qb + wave * 16;
    const int nt = job ? (18 - nt0) : nt0;

    const u16* qptr = Q + (size_t)(b * Sz + wq + lr) * Dm + h * HDm;
    bf16x8 qf[2];
    qf[0] = *(const bf16x8*)(qptr + lg * 8);
    qf[1] = *(const bf16x8*)(qptr + 32 + lg * 8);

    // per-row constant bias for fully-clamped windows: q . pos[511]
    float b511[4];
    {
      const u16* pp = posB + (NREL - 1) * HDm;
      f32x4 a = {};
      a = mfma16(qf[0], *(const bf16x8*)(pp + lg * 8), a);
      a = mfma16(qf[1], *(const bf16x8*)(pp + 32 + lg * 8), a);
      #pragma unroll
      for (int r = 0; r < 4; ++r) b511[r] = a[r];
    }

    f32x4 oacc[4] = {};
    float m_i[4], l_i[4];
    #pragma unroll
    for (int r = 0; r < 4; ++r) { m_i[r] = -1e30f; l_i[r] = 0.f; }

    for (int t = 0; t < nt; ++t, ++u) {
      const int j0 = t * 64;
      const int bsel = u & 1;
      const bool active = (j0 <= wq + 15);
      const bool allclamp = (wq - j0 - 63) >= NREL - 1;

      if (active && !allclamp) {
        // ---- windowed REL via MFMA (wave-private rows) ----
        const int wb = wq - j0 - 63;
        #pragma unroll
        for (int wg = 0; wg < 5; ++wg) {
          int prow = wb + wg * 16 + lr;
          prow = prow < 0 ? 0 : (prow > NREL - 1 ? NREL - 1 : prow);
          const u16* pp = posB + prow * HDm;
          f32x4 acc = {};
          acc = mfma16(qf[0], *(const bf16x8*)(pp + lg * 8), acc);
          acc = mfma16(qf[1], *(const bf16x8*)(pp + 32 + lg * 8), acc);
          #pragma unroll
          for (int r = 0; r < 4; ++r)
            SHW[(lg * 4 + r) * 88 + wg * 16 + lr] = f2bf(acc[r]);
        }
      }
      __builtin_amdgcn_sched_barrier(0);
      // prefetch next tile; counted vmcnt keeps it in flight across barrier
      if (u + 1 < 18) {
        issue(u + 1);
        asm volatile("s_waitcnt vmcnt(2)" ::: "memory");
      } else {
        asm volatile("s_waitcnt vmcnt(0)" ::: "memory");
      }
      __builtin_amdgcn_s_barrier();

      if (active) {
        // ---- QK^T + bias + mask ----
        float p_[4][4], tmax[4];
        #pragma unroll
        for (int r = 0; r < 4; ++r) tmax[r] = -3e38f;
        #pragma unroll
        for (int jg = 0; jg < 4; ++jg) {
          const int row = jg * 16 + lr;
          f32x4 a = {};
          a = mfma16(qf[0], *(const bf16x8*)&Ks[bsel][row * 64 + (((0 + lg) ^ (lr & 7)) * 8)], a);
          a = mfma16(qf[1], *(const bf16x8*)&Ks[bsel][row * 64 + (((4 + lg) ^ (lr & 7)) * 8)], a);
          #pragma unroll
          for (int r = 0; r < 4; ++r) {
            float s;
            if (allclamp) {
              s = (a[r] + b511[r]) * 0.125f;  // never masked, never windowed
            } else {
              const int w = lg * 4 + r - jg * 16 - lr + 63;  // in [0,78]
              float bias = bf2f(SHW[(lg * 4 + r) * 88 + w]);
              s = (a[r] + bias) * 0.125f;
              if (j0 + row > wq + lg * 4 + r) s = -1e9f;
            }
            p_[r][jg] = s;
            tmax[r] = fmaxf(tmax[r], s);
          }
        }
        #pragma unroll
        for (int msk = 1; msk < 16; msk <<= 1)
          #pragma unroll
          for (int r = 0; r < 4; ++r)
            tmax[r] = fmaxf(tmax[r], __shfl_xor(tmax[r], msk, 64));

        // defer-max: skip rescale when max growth small (P bounded by e^8)
        bool small = true;
        #pragma unroll
        for (int r = 0; r < 4; ++r) small = small && (tmax[r] <= m_i[r] + 8.f);
        if (!__all(small)) {
          #pragma unroll
          for (int r = 0; r < 4; ++r) {
            float mn = fmaxf(m_i[r], tmax[r]);
            float scale = __expf(m_i[r] - mn);
            m_i[r] = mn;
            l_i[r] *= scale;
            #pragma unroll
            for (int dg = 0; dg < 4; ++dg) oacc[dg][r] *= scale;
          }
        }

        float lsum[4];
        #pragma unroll
        for (int r = 0; r < 4; ++r) {
          float s0 = 0.f;
          #pragma unroll
          for (int jg = 0; jg < 4; ++jg) {
            p_[r][jg] = __expf(p_[r][jg] - m_i[r]);
            s0 += p_[r][jg];
          }
          lsum[r] = s0;
        }
        #pragma unroll
        for (int msk = 1; msk < 16; msk <<= 1)
          #pragma unroll
          for (int r = 0; r < 4; ++r)
            lsum[r] += __shfl_xor(lsum[r], msk, 64);
        #pragma unroll
        for (int r = 0; r < 4; ++r) l_i[r] += lsum[r];

        // ---- P -> per-wave LDS region ----
        #pragma unroll
        for (int r = 0; r < 4; ++r)
          #pragma unroll
          for (int jg = 0; jg < 4; ++jg)
            SHW[(lg * 4 + r) * 88 + jg * 16 + lr] = f2bf(p_[r][jg]);

        // ---- PV via hardware transpose reads ----
        #pragma unroll
        for (int kk = 0; kk < 2; ++kk) {
          bf16x8 pf = *(const bf16x8*)&SHW[lr * 88 + kk * 32 + lg * 8];
          u16x4 va[4][2];
          const int t0 = kk * 8 + lg * 2;
          #pragma unroll
          for (int dg = 0; dg < 4; ++dg) {
            const u16* base = &Vs[bsel][t0 * 256 + dg * 64 + lr * 4];
            va[dg][0] = tr0(base);
            va[dg][1] = tr512(base);
          }
          asm volatile("s_waitcnt lgkmcnt(0)" ::: "memory");
          __builtin_amdgcn_sched_barrier(0);
          #pragma unroll
          for (int dg = 0; dg < 4; ++dg)
            oacc[dg] = mfma16(pf, mk8(va[dg][0], va[dg][1]), oacc[dg]);
        }
      }
      __builtin_amdgcn_s_barrier();
    }

    // epilogue: normalize, store bf16
    #pragma unroll
    for (int r = 0; r < 4; ++r) {
      float inv = 1.0f / l_i[r];
      size_t orow = (size_t)(b * Sz + wq + lg * 4 + r) * Dm + h * HDm;
      #pragma unroll
      for (int dg = 0; dg < 4; ++dg)
        O[orow + dg * 16 + lr] = f2bf(oacc[dg][r] * inv);
    }
    qi = 7 - pr;
  }
}

// ---------------- launcher ----------------
extern "C" void kernel_launch(void* const* d_in, const int* in_sizes, int n_in,
                              void* d_out, int out_size, void* d_ws, size_t ws_size,
                              hipStream_t stream) {
  const float* query = (const float*)d_in[0];
  const float* key   = (const float*)d_in[1];
  const float* value = (const float*)d_in[2];
  const float* Wq    = (const float*)d_in[3];
  const float* bq    = (const float*)d_in[4];
  const float* Wk    = (const float*)d_in[5];
  const float* bk    = (const float*)d_in[6];
  const float* Wv    = (const float*)d_in[7];
  const float* bv    = (const float*)d_in[8];
  const float* Wo    = (const float*)d_in[9];
  const float* bo    = (const float*)d_in[10];
  const float* pos   = (const float*)d_in[11];

  char* ws = (char*)d_ws;
  u16* WqB  = (u16*)(ws);                 // 2 MB
  u16* WkB  = (u16*)(ws + (2ull << 20));  // 2 MB
  u16* WvB  = (u16*)(ws + (4ull << 20));  // 2 MB
  u16* WoB  = (u16*)(ws + (6ull << 20));  // 2 MB
  u16* posB = (u16*)(ws + (8ull << 20));  // 64 KB
  u16* Xq   = (u16*)(ws + (9ull << 20));  // 16 MB (reused as Ob)
  u16* Xk   = (u16*)(ws + (25ull << 20)); // 16 MB (reused as Vb)
  u16* Xv   = (u16*)(ws + (41ull << 20)); // 16 MB
  u16* Qb   = (u16*)(ws + (57ull << 20)); // 16 MB
  u16* Kb   = (u16*)(ws + (73ull << 20)); // 16 MB
  u16* Vb   = Xk;                         // Xk dead after K projection
  u16* Ob   = Xq;                         // Xq dead after Q projection

  cvt_kernel<<<1024, 256, 0, stream>>>(Wq, WqB);
  cvt_kernel<<<1024, 256, 0, stream>>>(Wk, WkB);
  cvt_kernel<<<1024, 256, 0, stream>>>(Wv, WvB);
  cvt_kernel<<<1024, 256, 0, stream>>>(Wo, WoB);
  cvt_kernel<<<32,   256, 0, stream>>>(pos, posB);
  cvt_kernel<<<8192, 256, 0, stream>>>(query, Xq);
  cvt_kernel<<<8192, 256, 0, stream>>>(key,   Xk);
  cvt_kernel<<<8192, 256, 0, stream>>>(value, Xv);

  dim3 ggrid(Dm / 128, Mrows / 128);
  gemm_bt<true><<<ggrid, 256, 0, stream>>>(Xq, WqB, bq, Qb);
  gemm_bt<true><<<ggrid, 256, 0, stream>>>(Xk, WkB, bk, Kb);
  gemm_bt<true><<<ggrid, 256, 0, stream>>>(Xv, WvB, bv, Vb);

  attn_kernel<<<512, 512, 0, stream>>>(Qb, Kb, Vb, posB, Ob);

  gemm_bt<false><<<ggrid, 256, 0, stream>>>(Ob, WoB, bo, d_out);
}

// Round 7
// 257.291 us; speedup vs baseline: 2.4878x; 1.0228x over previous
//
#include <hip/hip_runtime.h>
#include <stdint.h>

#define DEV __device__ __forceinline__

typedef unsigned short u16;
typedef __bf16 bf16x8 __attribute__((ext_vector_type(8)));
typedef float  f32x4  __attribute__((ext_vector_type(4)));
typedef unsigned short u16x8 __attribute__((ext_vector_type(8)));
typedef unsigned short u16x4 __attribute__((ext_vector_type(4)));
typedef float  fvec4  __attribute__((ext_vector_type(4)));

constexpr int Sz   = 1024;  // sequence length
constexpr int Dm   = 1024;  // model dim
constexpr int HDm  = 64;    // head size
constexpr int NREL = 512;
constexpr int Mrows = 8192; // B*S
constexpr int KV   = 32;    // KV tile rows

DEV u16 f2bf(float f) { return __builtin_bit_cast(u16, (__bf16)f); }
DEV float bf2f(u16 h) { return __builtin_bit_cast(float, (uint32_t)h << 16); }
DEV f32x4 mfma16(bf16x8 a, bf16x8 b, f32x4 c) {
  return __builtin_amdgcn_mfma_f32_16x16x32_bf16(a, b, c, 0, 0, 0);
}

// hardware transpose read. Lane l fetches 8B at its OWN addr; fixed cross-lane
// permute within each 16-lane group delivers elem j = region[(l&15) + 16j].
DEV u16x4 tr0(const u16* p) {
  u16x4 d;
  asm volatile("ds_read_b64_tr_b16 %0, %1"
               : "=v"(d)
               : "v"((const __attribute__((address_space(3))) u16*)p));
  return d;
}
DEV u16x4 tr512(const u16* p) {  // +512 bytes = next 4-row (j) subtile
  u16x4 d;
  asm volatile("ds_read_b64_tr_b16 %0, %1 offset:512"
               : "=v"(d)
               : "v"((const __attribute__((address_space(3))) u16*)p));
  return d;
}
DEV bf16x8 mk8(u16x4 a, u16x4 b) {
  u16x8 r;
  r[0] = a[0]; r[1] = a[1]; r[2] = a[2]; r[3] = a[3];
  r[4] = b[0]; r[5] = b[1]; r[6] = b[2]; r[7] = b[3];
  return __builtin_bit_cast(bf16x8, r);
}

// ---------------- fp32 -> bf16 conversion ----------------
__global__ __launch_bounds__(256) void cvt_kernel(const float* __restrict__ in,
                                                  u16* __restrict__ out) {
  size_t i = (size_t)blockIdx.x * 256 + threadIdx.x;
  fvec4 v = *(const fvec4*)(in + i * 4);
  u16x4 o;
  o[0] = f2bf(v[0]); o[1] = f2bf(v[1]); o[2] = f2bf(v[2]); o[3] = f2bf(v[3]);
  *(u16x4*)(out + i * 4) = o;
}

// ---------------- GEMM: C[m,n] = sum_k A[m,k]*Bw[n,k] + bias[n] ----------------
template<bool OUT_BF16>
__global__ __launch_bounds__(256) void gemm_bt(const u16* __restrict__ A,
                                               const u16* __restrict__ Bw,
                                               const float* __restrict__ bias,
                                               void* __restrict__ Cout) {
  __shared__ u16 As[128 * 64];
  __shared__ u16 Bs[128 * 64];
  const int tid = threadIdx.x;
  const int wave = tid >> 6, lane = tid & 63;
  const int lr = lane & 15, lg = lane >> 4;
  const int m0 = blockIdx.y * 128, n0 = blockIdx.x * 128;
  const int wr = (wave >> 1) * 64, wc = (wave & 1) * 64;
  f32x4 acc[4][4] = {};
  for (int k0 = 0; k0 < Dm; k0 += 64) {
    #pragma unroll
    for (int it = 0; it < 4; ++it) {
      int chunk = it * 256 + wave * 64 + lane;
      int row = chunk >> 3, c16 = chunk & 7;
      const u16* bsrc = Bw + (size_t)(n0 + row) * Dm + k0 + ((c16 ^ (row & 7)) * 8);
      __builtin_amdgcn_global_load_lds(
          (const __attribute__((address_space(1))) void*)bsrc,
          (__attribute__((address_space(3))) void*)&Bs[(it * 256 + wave * 64) * 8],
          16, 0, 0);
      const u16* asrc = A + (size_t)(m0 + row) * Dm + k0 + ((c16 ^ (row & 7)) * 8);
      __builtin_amdgcn_global_load_lds(
          (const __attribute__((address_space(1))) void*)asrc,
          (__attribute__((address_space(3))) void*)&As[(it * 256 + wave * 64) * 8],
          16, 0, 0);
    }
    __syncthreads();
    #pragma unroll
    for (int kk = 0; kk < 2; ++kk) {
      bf16x8 af[4], bf_[4];
      #pragma unroll
      for (int m = 0; m < 4; ++m)
        af[m] = *(const bf16x8*)&As[(wr + m * 16 + lr) * 64 + (((kk * 4 + lg) ^ (lr & 7)) * 8)];
      #pragma unroll
      for (int n = 0; n < 4; ++n)
        bf_[n] = *(const bf16x8*)&Bs[(wc + n * 16 + lr) * 64 + (((kk * 4 + lg) ^ (lr & 7)) * 8)];
      #pragma unroll
      for (int m = 0; m < 4; ++m)
        #pragma unroll
        for (int n = 0; n < 4; ++n)
          acc[m][n] = mfma16(af[m], bf_[n], acc[m][n]);
    }
    __syncthreads();
  }
  float bv[4];
  #pragma unroll
  for (int n = 0; n < 4; ++n) bv[n] = bias[n0 + wc + n * 16 + lr];
  #pragma unroll
  for (int m = 0; m < 4; ++m) {
    #pragma unroll
    for (int n = 0; n < 4; ++n) {
      const int gcol = n0 + wc + n * 16 + lr;
      #pragma unroll
      for (int r = 0; r < 4; ++r) {
        const int grow = m0 + wr + m * 16 + lg * 4 + r;
        float v = acc[m][n][r] + bv[n];
        if (OUT_BF16)
          ((u16*)Cout)[(size_t)grow * Dm + gcol] = f2bf(v);
        else
          ((float*)Cout)[(size_t)grow * Dm + gcol] = v;
      }
    }
  }
}

// ---------------- fused causal attention with relative-position bias ----------------
// 2048 blocks x 256 threads (4 waves). Block = one (b,h) + one 64-row q chunk.
// KV tiles of 32, double-buffered, counted vmcnt(2). REL bias stored by COLUMN
// ([16][32] per wave, stride 40). Row-sum l via MFMA against ones. 21 KB LDS +
// VGPR<=64 -> 7 blocks/CU (28 waves).
__global__ __launch_bounds__(256, 8) void attn_kernel(const u16* __restrict__ Q,
                                                      const u16* __restrict__ Kb,
                                                      const u16* __restrict__ Vb,
                                                      const u16* __restrict__ posB,
                                                      u16* __restrict__ O) {
  __shared__ u16 Ks[2][KV * 64];   // K tiles, XOR-swizzled 16B granules
  __shared__ u16 Vs[2][KV * 64];   // V tiles subtiled [j>>2][d>>4][j&3][d&15]
  __shared__ u16 SH[4][16 * 40];   // per-wave: bias-by-col [q][col] / P [q][col], stride 40

  const int tid = threadIdx.x;
  const int wave = tid >> 6, lane = tid & 63;
  const int lr = lane & 15, lg = lane >> 4;
  // XCD-clustered: each XCD owns 16 (b,h) pairs (4 MB K/V = one L2). Heavy
  // q-chunks launch first (qi descending) for backfill balance.
  const int bid = blockIdx.x;
  const int xcd = bid & 7;
  const int idx = bid >> 3;        // 0..255
  const int bhl = idx & 15;
  const int qi  = 15 - (idx >> 4); // 15..0, heavy first
  const int bh  = xcd * 16 + bhl;
  const int b = bh >> 4, h = bh & 15;
  const int qb = qi * 64;
  const int wq = qb + wave * 16;
  u16* SHW = SH[wave];

  const u16* qptr = Q + (size_t)(b * Sz + wq + lr) * Dm + h * HDm;
  bf16x8 qf[2];
  qf[0] = *(const bf16x8*)(qptr + lg * 8);
  qf[1] = *(const bf16x8*)(qptr + 32 + lg * 8);

  // staging source indices (one 16B chunk per thread per tile, slot = tid)
  const int krow = tid >> 3, kc = tid & 7;            // K: row-major swizzled
  const int vj = ((tid >> 5) << 2) | ((tid >> 1) & 3);// V: subtile layout
  const int vd = ((tid >> 3) & 3) * 16 + (tid & 1) * 8;

  auto issue = [&](int t) {
    const int j0 = t * KV;
    const int bsel = t & 1;
    const u16* ksrc = Kb + (size_t)(b * Sz + j0 + krow) * Dm + h * HDm + ((kc ^ (krow & 7)) * 8);
    __builtin_amdgcn_global_load_lds(
        (const __attribute__((address_space(1))) void*)ksrc,
        (__attribute__((address_space(3))) void*)&Ks[bsel][wave * 512],
        16, 0, 0);
    const u16* vsrc = Vb + (size_t)(b * Sz + j0 + vj) * Dm + h * HDm + vd;
    __builtin_amdgcn_global_load_lds(
        (const __attribute__((address_space(1))) void*)vsrc,
        (__attribute__((address_space(3))) void*)&Vs[bsel][wave * 512],
        16, 0, 0);
  };

  issue(0);

  f32x4 oacc[4] = {};
  float m_i[4], l_i[4];
  #pragma unroll
  for (int r = 0; r < 4; ++r) { m_i[r] = -1e30f; l_i[r] = 0.f; }

  const int nt = 2 * qi + 2;
  for (int t = 0; t < nt; ++t) {
    const int j0 = t * KV;
    const int bsel = t & 1;
    const bool active = (j0 <= wq + 15);
    const int wb = wq - j0 - 31;

    if (active) {
      // ---- REL bias via MFMA, stored by column: SHW[q*40 + col] ----
      // col = q - w + 31; coverage of col 0..31 proven complete over wg 0..2.
      #pragma unroll
      for (int wg = 0; wg < 3; ++wg) {
        int prow = wb + wg * 16 + lr;
        prow = prow < 0 ? 0 : (prow > NREL - 1 ? NREL - 1 : prow);
        const u16* pp = posB + prow * HDm;
        f32x4 a = {};
        a = mfma16(qf[0], *(const bf16x8*)(pp + lg * 8), a);
        a = mfma16(qf[1], *(const bf16x8*)(pp + 32 + lg * 8), a);
        #pragma unroll
        for (int r = 0; r < 4; ++r) {
          const int q = lg * 4 + r;
          const int col = q - (wg * 16 + lr) + 31;
          if (col >= 0 && col < 32)
            SHW[q * 40 + col] = f2bf(a[r]);
        }
      }
    }
    __builtin_amdgcn_sched_barrier(0);
    // prefetch next tile; counted vmcnt keeps it in flight across barrier
    if (t + 1 < nt) {
      issue(t + 1);
      asm volatile("s_waitcnt vmcnt(2)" ::: "memory");
    } else {
      asm volatile("s_waitcnt vmcnt(0)" ::: "memory");
    }
    __builtin_amdgcn_s_barrier();

    if (active) {
      // ---- QK^T + bias + mask ----
      float p_[4][2], tmax[4];
      #pragma unroll
      for (int r = 0; r < 4; ++r) tmax[r] = -3e38f;
      #pragma unroll
      for (int jg = 0; jg < 2; ++jg) {
        const int row = jg * 16 + lr;
        f32x4 a = {};
        a = mfma16(qf[0], *(const bf16x8*)&Ks[bsel][row * 64 + (((0 + lg) ^ (lr & 7)) * 8)], a);
        a = mfma16(qf[1], *(const bf16x8*)&Ks[bsel][row * 64 + (((4 + lg) ^ (lr & 7)) * 8)], a);
        #pragma unroll
        for (int r = 0; r < 4; ++r) {
          const int q = lg * 4 + r;
          float bias = bf2f(SHW[q * 40 + jg * 16 + lr]);
          float s = (a[r] + bias) * 0.125f;
          if (j0 + row > wq + q) s = -1e9f;
          p_[r][jg] = s;
          tmax[r] = fmaxf(tmax[r], s);
        }
      }
      #pragma unroll
      for (int msk = 1; msk < 16; msk <<= 1)
        #pragma unroll
        for (int r = 0; r < 4; ++r)
          tmax[r] = fmaxf(tmax[r], __shfl_xor(tmax[r], msk, 64));

      // defer-max: skip rescale when max growth small (P bounded by e^8)
      bool small = true;
      #pragma unroll
      for (int r = 0; r < 4; ++r) small = small && (tmax[r] <= m_i[r] + 8.f);
      if (!__all(small)) {
        #pragma unroll
        for (int r = 0; r < 4; ++r) {
          float mn = fmaxf(m_i[r], tmax[r]);
          float scale = __expf(m_i[r] - mn);
          m_i[r] = mn;
          l_i[r] *= scale;
          #pragma unroll
          for (int dg = 0; dg < 4; ++dg) oacc[dg][r] *= scale;
        }
      }

      // exp + P -> LDS (overwrites bias region; bias reads already done)
      #pragma unroll
      for (int r = 0; r < 4; ++r)
        #pragma unroll
        for (int jg = 0; jg < 2; ++jg) {
          p_[r][jg] = __expf(p_[r][jg] - m_i[r]);
          SHW[(lg * 4 + r) * 40 + jg * 16 + lr] = f2bf(p_[r][jg]);
        }

      // P fragment (A operand): lane holds P[lr][lg*8..+8]
      bf16x8 pf = *(const bf16x8*)&SHW[lr * 40 + lg * 8];

      // row-sum via MFMA against ones: D[q][*] = sum_j P[q][j]
      u16x8 ov;
      #pragma unroll
      for (int e = 0; e < 8; ++e) ov[e] = 0x3F80;
      f32x4 z = {};
      f32x4 lsumv = mfma16(pf, __builtin_bit_cast(bf16x8, ov), z);
      #pragma unroll
      for (int r = 0; r < 4; ++r) l_i[r] += lsumv[r];

      // ---- PV via hardware transpose reads (single K=32 MFMA per dg) ----
      u16x4 va[4][2];
      #pragma unroll
      for (int dg = 0; dg < 4; ++dg) {
        const u16* base = &Vs[bsel][(2 * lg) * 256 + dg * 64 + lr * 4];
        va[dg][0] = tr0(base);
        va[dg][1] = tr512(base);
      }
      asm volatile("s_waitcnt lgkmcnt(0)" ::: "memory");
      __builtin_amdgcn_sched_barrier(0);
      #pragma unroll
      for (int dg = 0; dg < 4; ++dg)
        oacc[dg] = mfma16(pf, mk8(va[dg][0], va[dg][1]), oacc[dg]);
    }
    __builtin_amdgcn_s_barrier();
  }

  // epilogue: normalize, store bf16
  #pragma unroll
  for (int r = 0; r < 4; ++r) {
    float inv = 1.0f / l_i[r];
    size_t orow = (size_t)(b * Sz + wq + lg * 4 + r) * Dm + h * HDm;
    #pragma unroll
    for (int dg = 0; dg < 4; ++dg)
      O[orow + dg * 16 + lr] = f2bf(oacc[dg][r] * inv);
  }
}

// ---------------- launcher ----------------
extern "C" void kernel_launch(void* const* d_in, const int* in_sizes, int n_in,
                              void* d_out, int out_size, void* d_ws, size_t ws_size,
                              hipStream_t stream) {
  const float* query = (const float*)d_in[0];
  const float* key   = (const float*)d_in[1];
  const float* value = (const float*)d_in[2];
  const float* Wq    = (const float*)d_in[3];
  const float* bq    = (const float*)d_in[4];
  const float* Wk    = (const float*)d_in[5];
  const float* bk    = (const float*)d_in[6];
  const float* Wv    = (const float*)d_in[7];
  const float* bv    = (const float*)d_in[8];
  const float* Wo    = (const float*)d_in[9];
  const float* bo    = (const float*)d_in[10];
  const float* pos   = (const float*)d_in[11];

  char* ws = (char*)d_ws;
  u16* WqB  = (u16*)(ws);                 // 2 MB
  u16* WkB  = (u16*)(ws + (2ull << 20));  // 2 MB
  u16* WvB  = (u16*)(ws + (4ull << 20));  // 2 MB
  u16* WoB  = (u16*)(ws + (6ull << 20));  // 2 MB
  u16* posB = (u16*)(ws + (8ull << 20));  // 64 KB
  u16* Xq   = (u16*)(ws + (9ull << 20));  // 16 MB (reused as Ob)
  u16* Xk   = (u16*)(ws + (25ull << 20)); // 16 MB (reused as Vb)
  u16* Xv   = (u16*)(ws + (41ull << 20)); // 16 MB
  u16* Qb   = (u16*)(ws + (57ull << 20)); // 16 MB
  u16* Kb   = (u16*)(ws + (73ull << 20)); // 16 MB
  u16* Vb   = Xk;                         // Xk dead after K projection
  u16* Ob   = Xq;                         // Xq dead after Q projection

  cvt_kernel<<<1024, 256, 0, stream>>>(Wq, WqB);
  cvt_kernel<<<1024, 256, 0, stream>>>(Wk, WkB);
  cvt_kernel<<<1024, 256, 0, stream>>>(Wv, WvB);
  cvt_kernel<<<1024, 256, 0, stream>>>(Wo, WoB);
  cvt_kernel<<<32,   256, 0, stream>>>(pos, posB);
  cvt_kernel<<<8192, 256, 0, stream>>>(query, Xq);
  cvt_kernel<<<8192, 256, 0, stream>>>(key,   Xk);
  cvt_kernel<<<8192, 256, 0, stream>>>(value, Xv);

  dim3 ggrid(Dm / 128, Mrows / 128);
  gemm_bt<true><<<ggrid, 256, 0, stream>>>(Xq, WqB, bq, Qb);
  gemm_bt<true><<<ggrid, 256, 0, stream>>>(Xk, WkB, bk, Kb);
  gemm_bt<true><<<ggrid, 256, 0, stream>>>(Xv, WvB, bv, Vb);

  attn_kernel<<<2048, 256, 0, stream>>>(Qb, Kb, Vb, posB, Ob);

  gemm_bt<false><<<ggrid, 256, 0, stream>>>(Ob, WoB, bo, d_out);
}

// Round 8
// 250.875 us; speedup vs baseline: 2.5514x; 1.0256x over previous
//
#include <hip/hip_runtime.h>
#include <stdint.h>

#define DEV __device__ __forceinline__

typedef unsigned short u16;
typedef __bf16 bf16x8 __attribute__((ext_vector_type(8)));
typedef float  f32x4  __attribute__((ext_vector_type(4)));
typedef unsigned short u16x8 __attribute__((ext_vector_type(8)));
typedef unsigned short u16x4 __attribute__((ext_vector_type(4)));
typedef float  fvec4  __attribute__((ext_vector_type(4)));

constexpr int Sz   = 1024;  // sequence length
constexpr int Dm   = 1024;  // model dim
constexpr int HDm  = 64;    // head size
constexpr int NREL = 512;
constexpr int Mrows = 8192; // B*S
constexpr int KV   = 32;    // KV tile rows

DEV u16 f2bf(float f) { return __builtin_bit_cast(u16, (__bf16)f); }
DEV float bf2f(u16 h) { return __builtin_bit_cast(float, (uint32_t)h << 16); }
DEV f32x4 mfma16(bf16x8 a, bf16x8 b, f32x4 c) {
  return __builtin_amdgcn_mfma_f32_16x16x32_bf16(a, b, c, 0, 0, 0);
}
DEV float ex2(float x) {  // v_exp_f32 computes 2^x
  float r;
  asm("v_exp_f32 %0, %1" : "=v"(r) : "v"(x));
  return r;
}

// hardware transpose read. Lane l fetches 8B at its OWN addr; fixed cross-lane
// permute within each 16-lane group delivers elem j = region[(l&15) + 16j].
DEV u16x4 tr0(const u16* p) {
  u16x4 d;
  asm volatile("ds_read_b64_tr_b16 %0, %1"
               : "=v"(d)
               : "v"((const __attribute__((address_space(3))) u16*)p));
  return d;
}
DEV u16x4 tr512(const u16* p) {  // +512 bytes = next 4-row (j) subtile
  u16x4 d;
  asm volatile("ds_read_b64_tr_b16 %0, %1 offset:512"
               : "=v"(d)
               : "v"((const __attribute__((address_space(3))) u16*)p));
  return d;
}
DEV bf16x8 mk8(u16x4 a, u16x4 b) {
  u16x8 r;
  r[0] = a[0]; r[1] = a[1]; r[2] = a[2]; r[3] = a[3];
  r[4] = b[0]; r[5] = b[1]; r[6] = b[2]; r[7] = b[3];
  return __builtin_bit_cast(bf16x8, r);
}

// ---------------- fp32 -> bf16 conversion ----------------
__global__ __launch_bounds__(256) void cvt_kernel(const float* __restrict__ in,
                                                  u16* __restrict__ out) {
  size_t i = (size_t)blockIdx.x * 256 + threadIdx.x;
  fvec4 v = *(const fvec4*)(in + i * 4);
  u16x4 o;
  o[0] = f2bf(v[0]); o[1] = f2bf(v[1]); o[2] = f2bf(v[2]); o[3] = f2bf(v[3]);
  *(u16x4*)(out + i * 4) = o;
}

// ---------------- GEMM: C[m,n] = sum_k A[m,k]*Bw[n,k] + bias[n] ----------------
template<bool OUT_BF16>
__global__ __launch_bounds__(256) void gemm_bt(const u16* __restrict__ A,
                                               const u16* __restrict__ Bw,
                                               const float* __restrict__ bias,
                                               void* __restrict__ Cout) {
  __shared__ u16 As[128 * 64];
  __shared__ u16 Bs[128 * 64];
  const int tid = threadIdx.x;
  const int wave = tid >> 6, lane = tid & 63;
  const int lr = lane & 15, lg = lane >> 4;
  const int m0 = blockIdx.y * 128, n0 = blockIdx.x * 128;
  const int wr = (wave >> 1) * 64, wc = (wave & 1) * 64;
  f32x4 acc[4][4] = {};
  for (int k0 = 0; k0 < Dm; k0 += 64) {
    #pragma unroll
    for (int it = 0; it < 4; ++it) {
      int chunk = it * 256 + wave * 64 + lane;
      int row = chunk >> 3, c16 = chunk & 7;
      const u16* bsrc = Bw + (size_t)(n0 + row) * Dm + k0 + ((c16 ^ (row & 7)) * 8);
      __builtin_amdgcn_global_load_lds(
          (const __attribute__((address_space(1))) void*)bsrc,
          (__attribute__((address_space(3))) void*)&Bs[(it * 256 + wave * 64) * 8],
          16, 0, 0);
      const u16* asrc = A + (size_t)(m0 + row) * Dm + k0 + ((c16 ^ (row & 7)) * 8);
      __builtin_amdgcn_global_load_lds(
          (const __attribute__((address_space(1))) void*)asrc,
          (__attribute__((address_space(3))) void*)&As[(it * 256 + wave * 64) * 8],
          16, 0, 0);
    }
    __syncthreads();
    #pragma unroll
    for (int kk = 0; kk < 2; ++kk) {
      bf16x8 af[4], bf_[4];
      #pragma unroll
      for (int m = 0; m < 4; ++m)
        af[m] = *(const bf16x8*)&As[(wr + m * 16 + lr) * 64 + (((kk * 4 + lg) ^ (lr & 7)) * 8)];
      #pragma unroll
      for (int n = 0; n < 4; ++n)
        bf_[n] = *(const bf16x8*)&Bs[(wc + n * 16 + lr) * 64 + (((kk * 4 + lg) ^ (lr & 7)) * 8)];
      #pragma unroll
      for (int m = 0; m < 4; ++m)
        #pragma unroll
        for (int n = 0; n < 4; ++n)
          acc[m][n] = mfma16(af[m], bf_[n], acc[m][n]);
    }
    __syncthreads();
  }
  float bv[4];
  #pragma unroll
  for (int n = 0; n < 4; ++n) bv[n] = bias[n0 + wc + n * 16 + lr];
  #pragma unroll
  for (int m = 0; m < 4; ++m) {
    #pragma unroll
    for (int n = 0; n < 4; ++n) {
      const int gcol = n0 + wc + n * 16 + lr;
      #pragma unroll
      for (int r = 0; r < 4; ++r) {
        const int grow = m0 + wr + m * 16 + lg * 4 + r;
        float v = acc[m][n][r] + bv[n];
        if (OUT_BF16)
          ((u16*)Cout)[(size_t)grow * Dm + gcol] = f2bf(v);
        else
          ((float*)Cout)[(size_t)grow * Dm + gcol] = v;
      }
    }
  }
}

// ---------------- fused causal attention with relative-position bias ----------------
// 2048 blocks x 256 threads (4 waves). Block = one (b,h) + one 64-row q chunk.
// SWAPPED-OPERAND scheme: S^T = mfma(K, Q) -> each lane owns ONE q row (q = wq+lr)
// with 8 j-values in-register; softmax is in-lane + 2 shuffles; m/l are scalars.
// PV = mfma(V^T, P) -> O^T; epilogue packs 4x8B stores. Base-2 exp domain.
__global__ __launch_bounds__(256, 8) void attn_kernel(const u16* __restrict__ Q,
                                                      const u16* __restrict__ Kb,
                                                      const u16* __restrict__ Vb,
                                                      const u16* __restrict__ posB,
                                                      u16* __restrict__ O) {
  __shared__ u16 Ks[2][KV * 64];   // K tiles, XOR-swizzled 16B granules
  __shared__ u16 Vs[2][KV * 64];   // V tiles subtiled [j>>2][d>>4][j&3][d&15]
  __shared__ u16 SH[4][16 * 40];   // per-wave: bias-by-col [q][col] / P [q][col], stride 40

  const int tid = threadIdx.x;
  const int wave = tid >> 6, lane = tid & 63;
  const int lr = lane & 15, lg = lane >> 4;
  // XCD-clustered: each XCD owns 16 (b,h) pairs (4 MB K/V = one L2). Heavy
  // q-chunks launch first (qi descending) for backfill balance.
  const int bid = blockIdx.x;
  const int xcd = bid & 7;
  const int idx = bid >> 3;        // 0..255
  const int bhl = idx & 15;
  const int qi  = 15 - (idx >> 4); // 15..0, heavy first
  const int bh  = xcd * 16 + bhl;
  const int b = bh >> 4, h = bh & 15;
  const int qb = qi * 64;
  const int wq = qb + wave * 16;
  u16* SHW = SH[wave];

  const u16* qptr = Q + (size_t)(b * Sz + wq + lr) * Dm + h * HDm;
  bf16x8 qf[2];
  qf[0] = *(const bf16x8*)(qptr + lg * 8);
  qf[1] = *(const bf16x8*)(qptr + 32 + lg * 8);

  // staging source indices (one 16B chunk per thread per tile, slot = tid)
  const int krow = tid >> 3, kc = tid & 7;            // K: row-major swizzled
  const int vj = ((tid >> 5) << 2) | ((tid >> 1) & 3);// V: subtile layout
  const int vd = ((tid >> 3) & 3) * 16 + (tid & 1) * 8;

  auto issue = [&](int t) {
    const int j0 = t * KV;
    const int bsel = t & 1;
    const u16* ksrc = Kb + (size_t)(b * Sz + j0 + krow) * Dm + h * HDm + ((kc ^ (krow & 7)) * 8);
    __builtin_amdgcn_global_load_lds(
        (const __attribute__((address_space(1))) void*)ksrc,
        (__attribute__((address_space(3))) void*)&Ks[bsel][wave * 512],
        16, 0, 0);
    const u16* vsrc = Vb + (size_t)(b * Sz + j0 + vj) * Dm + h * HDm + vd;
    __builtin_amdgcn_global_load_lds(
        (const __attribute__((address_space(1))) void*)vsrc,
        (__attribute__((address_space(3))) void*)&Vs[bsel][wave * 512],
        16, 0, 0);
  };

  issue(0);

  constexpr float SC = 0.125f * 1.44269504f;  // 1/sqrt(64) * log2(e)
  f32x4 oacc[4] = {};
  float m_i = -1e30f, l_i = 0.f;
  const int qg = wq + lr;  // this lane's global q row

  const int nt = 2 * qi + 2;
  for (int t = 0; t < nt; ++t) {
    const int j0 = t * KV;
    const int bsel = t & 1;
    const bool active = (j0 <= wq + 15);
    const int wb = wq - j0 - 31;

    if (active) {
      // ---- REL bias via MFMA, stored by column: SHW[q*40 + col] ----
      // slot [q][col] gets q_row . pos[clip((wq+q)-(j0+col))]
      #pragma unroll
      for (int wg = 0; wg < 3; ++wg) {
        int prow = wb + wg * 16 + lr;
        prow = prow < 0 ? 0 : (prow > NREL - 1 ? NREL - 1 : prow);
        const u16* pp = posB + prow * HDm;
        f32x4 a = {};
        a = mfma16(qf[0], *(const bf16x8*)(pp + lg * 8), a);
        a = mfma16(qf[1], *(const bf16x8*)(pp + 32 + lg * 8), a);
        #pragma unroll
        for (int r = 0; r < 4; ++r) {
          const int q = lg * 4 + r;
          const int col = q - (wg * 16 + lr) + 31;
          if (col >= 0 && col < 32)
            SHW[q * 40 + col] = f2bf(a[r]);
        }
      }
    }
    __builtin_amdgcn_sched_barrier(0);
    // prefetch next tile; counted vmcnt keeps it in flight across barrier
    if (t + 1 < nt) {
      issue(t + 1);
      asm volatile("s_waitcnt vmcnt(2)" ::: "memory");
    } else {
      asm volatile("s_waitcnt vmcnt(0)" ::: "memory");
    }
    __builtin_amdgcn_s_barrier();

    if (active) {
      // ---- swapped QK^T: lane owns q=qg, j = j0 + m*16 + lg*4 + r ----
      f32x4 s0 = {}, s1 = {};
      s0 = mfma16(*(const bf16x8*)&Ks[bsel][(0 + lr) * 64 + (((0 + lg) ^ (lr & 7)) * 8)], qf[0], s0);
      s0 = mfma16(*(const bf16x8*)&Ks[bsel][(0 + lr) * 64 + (((4 + lg) ^ (lr & 7)) * 8)], qf[1], s0);
      s1 = mfma16(*(const bf16x8*)&Ks[bsel][(16 + lr) * 64 + (((0 + lg) ^ (lr & 7)) * 8)], qf[0], s1);
      s1 = mfma16(*(const bf16x8*)&Ks[bsel][(16 + lr) * 64 + (((4 + lg) ^ (lr & 7)) * 8)], qf[1], s1);

      // bias gather: this lane's 8 slots of its own q-row (contiguous 8B x2)
      u16x4 bv0 = *(const u16x4*)&SHW[lr * 40 + lg * 4];
      u16x4 bv1 = *(const u16x4*)&SHW[lr * 40 + 16 + lg * 4];

      float p0[4], p1[4];
      float tmax = -3e38f;
      #pragma unroll
      for (int r = 0; r < 4; ++r) {
        float v0 = (s0[r] + bf2f(bv0[r])) * SC;
        if (j0 + lg * 4 + r > qg) v0 = -1e9f;
        p0[r] = v0; tmax = fmaxf(tmax, v0);
        float v1 = (s1[r] + bf2f(bv1[r])) * SC;
        if (j0 + 16 + lg * 4 + r > qg) v1 = -1e9f;
        p1[r] = v1; tmax = fmaxf(tmax, v1);
      }
      tmax = fmaxf(tmax, __shfl_xor(tmax, 16));
      tmax = fmaxf(tmax, __shfl_xor(tmax, 32));

      // defer-max (base-2 units: 11.5 ~ e^8)
      if (!__all(tmax <= m_i + 11.5f)) {
        float mn = fmaxf(m_i, tmax);
        float sc = ex2(m_i - mn);
        m_i = mn; l_i *= sc;
        #pragma unroll
        for (int dg = 0; dg < 4; ++dg) oacc[dg] *= sc;
      }

      float lsum = 0.f;
      #pragma unroll
      for (int r = 0; r < 4; ++r) {
        p0[r] = ex2(p0[r] - m_i); lsum += p0[r];
        p1[r] = ex2(p1[r] - m_i); lsum += p1[r];
      }
      lsum += __shfl_xor(lsum, 16);
      lsum += __shfl_xor(lsum, 32);
      l_i += lsum;

      // ---- P pack -> own q-row slots (overwrites bias; same-lane slots) ----
      u16x4 pk0, pk1;
      #pragma unroll
      for (int r = 0; r < 4; ++r) { pk0[r] = f2bf(p0[r]); pk1[r] = f2bf(p1[r]); }
      *(u16x4*)&SHW[lr * 40 + lg * 4] = pk0;
      *(u16x4*)&SHW[lr * 40 + 16 + lg * 4] = pk1;

      // P as B-operand: lane lr = row q, k-slice lg*8..+8
      bf16x8 pB = *(const bf16x8*)&SHW[lr * 40 + lg * 8];

      // ---- PV: O^T = V^T x P via tr-read V fragments as A-operand ----
      u16x4 va[4][2];
      #pragma unroll
      for (int dg = 0; dg < 4; ++dg) {
        const u16* base = &Vs[bsel][(2 * lg) * 256 + dg * 64 + lr * 4];
        va[dg][0] = tr0(base);
        va[dg][1] = tr512(base);
      }
      asm volatile("s_waitcnt lgkmcnt(0)" ::: "memory");
      __builtin_amdgcn_sched_barrier(0);
      #pragma unroll
      for (int dg = 0; dg < 4; ++dg)
        oacc[dg] = mfma16(mk8(va[dg][0], va[dg][1]), pB, oacc[dg]);
    }
    __builtin_amdgcn_s_barrier();
  }

  // epilogue: lane holds O^T[d = dg*16+lg*4+r][q = qg]; 4 x 8B stores
  const float inv = 1.0f / l_i;
  const size_t obase = (size_t)(b * Sz + qg) * Dm + h * HDm;
  #pragma unroll
  for (int dg = 0; dg < 4; ++dg) {
    u16x4 w;
    #pragma unroll
    for (int r = 0; r < 4; ++r) w[r] = f2bf(oacc[dg][r] * inv);
    *(u16x4*)&O[obase + dg * 16 + lg * 4] = w;
  }
}

// ---------------- launcher ----------------
extern "C" void kernel_launch(void* const* d_in, const int* in_sizes, int n_in,
                              void* d_out, int out_size, void* d_ws, size_t ws_size,
                              hipStream_t stream) {
  const float* query = (const float*)d_in[0];
  const float* key   = (const float*)d_in[1];
  const float* value = (const float*)d_in[2];
  const float* Wq    = (const float*)d_in[3];
  const float* bq    = (const float*)d_in[4];
  const float* Wk    = (const float*)d_in[5];
  const float* bk    = (const float*)d_in[6];
  const float* Wv    = (const float*)d_in[7];
  const float* bv    = (const float*)d_in[8];
  const float* Wo    = (const float*)d_in[9];
  const float* bo    = (const float*)d_in[10];
  const float* pos   = (const float*)d_in[11];

  char* ws = (char*)d_ws;
  u16* WqB  = (u16*)(ws);                 // 2 MB
  u16* WkB  = (u16*)(ws + (2ull << 20));  // 2 MB
  u16* WvB  = (u16*)(ws + (4ull << 20));  // 2 MB
  u16* WoB  = (u16*)(ws + (6ull << 20));  // 2 MB
  u16* posB = (u16*)(ws + (8ull << 20));  // 64 KB
  u16* Xq   = (u16*)(ws + (9ull << 20));  // 16 MB (reused as Ob)
  u16* Xk   = (u16*)(ws + (25ull << 20)); // 16 MB (reused as Vb)
  u16* Xv   = (u16*)(ws + (41ull << 20)); // 16 MB
  u16* Qb   = (u16*)(ws + (57ull << 20)); // 16 MB
  u16* Kb   = (u16*)(ws + (73ull << 20)); // 16 MB
  u16* Vb   = Xk;                         // Xk dead after K projection
  u16* Ob   = Xq;                         // Xq dead after Q projection

  cvt_kernel<<<1024, 256, 0, stream>>>(Wq, WqB);
  cvt_kernel<<<1024, 256, 0, stream>>>(Wk, WkB);
  cvt_kernel<<<1024, 256, 0, stream>>>(Wv, WvB);
  cvt_kernel<<<1024, 256, 0, stream>>>(Wo, WoB);
  cvt_kernel<<<32,   256, 0, stream>>>(pos, posB);
  cvt_kernel<<<8192, 256, 0, stream>>>(query, Xq);
  cvt_kernel<<<8192, 256, 0, stream>>>(key,   Xk);
  cvt_kernel<<<8192, 256, 0, stream>>>(value, Xv);

  dim3 ggrid(Dm / 128, Mrows / 128);
  gemm_bt<true><<<ggrid, 256, 0, stream>>>(Xq, WqB, bq, Qb);
  gemm_bt<true><<<ggrid, 256, 0, stream>>>(Xk, WkB, bk, Kb);
  gemm_bt<true><<<ggrid, 256, 0, stream>>>(Xv, WvB, bv, Vb);

  attn_kernel<<<2048, 256, 0, stream>>>(Qb, Kb, Vb, posB, Ob);

  gemm_bt<false><<<ggrid, 256, 0, stream>>>(Ob, WoB, bo, d_out);
}